// Round 1
// baseline (475.419 us; speedup 1.0000x reference)
//
#include <hip/hip_runtime.h>

// AVWGCN: B=32, N=2048, C=64, O=64, K=3, D=16
// Pipeline (all bf16 MFMA GEMMs in m97 style: 128x128 tile, BK=32, global_load_lds w=16):
//  1. supports_softmax: softmax(relu(E E^T)) rows -> Acat[:, 0:2048] (bf16)
//  2. cast_adj:  adj -> Acat[:, 2048:4096] (bf16)
//  3. cast_saw:  sa_weight -> saw_bf (bf16, already in Bt layout [j][t])
//  4. build_xtT: x[b,m,c] -> XtT[(b*64+c)][m] (bf16, Bt layout for aggregation GEMMs)
//  5. gemm<1>:   z = Acat @ saw_bf^T, fused epilogue: S = sig(z)*adj + (1-sig(z))*sup -> S_bf
//  6. transpose: S_bf -> St_bf (aliases Acat)
//  7. gemm<2>:   T2 = 2*(S_bf @ St_bf^T) - I -> T2_bf (aliases saw_bf)
//  8. gemm<0>:   xg1 = S_bf @ XtT^T (fp32)
//  9. gemm<0>:   xg2 = T2_bf @ XtT^T (fp32)
// 10. gconv: per node n: weights_n = sum_d E[n,d]*Wp[d], out[b,n,:] = sum_{k,i} xg_k[b,i]*w[k,i,:] + bias_n
// Workspace: 80 MB total (aliased).

typedef unsigned short u16;
typedef float f32x4 __attribute__((ext_vector_type(4)));
typedef __bf16 bf16x8 __attribute__((ext_vector_type(8)));
typedef unsigned short u16x8 __attribute__((ext_vector_type(8)));

__device__ __forceinline__ u16 f2bf(float f) {
    unsigned u = __float_as_uint(f);
    u += 0x7FFFu + ((u >> 16) & 1u);   // RNE
    return (u16)(u >> 16);
}
__device__ __forceinline__ float bf2f(u16 h) {
    return __uint_as_float((unsigned)h << 16);
}
__device__ __forceinline__ void gl_lds16(const void* g, void* l) {
    __builtin_amdgcn_global_load_lds(
        (const __attribute__((address_space(1))) unsigned*)g,
        (__attribute__((address_space(3))) unsigned*)l, 16, 0, 0);
}

// ---------------------------------------------------------------- supports
__global__ __launch_bounds__(256)
void supports_softmax(const float* __restrict__ E, u16* __restrict__ Acat) {
    const int n = blockIdx.x, tid = threadIdx.x;
    const int lane = tid & 63, wave = tid >> 6;
    __shared__ float red[4];
    float e[16];
#pragma unroll
    for (int d = 0; d < 16; ++d) e[d] = E[n * 16 + d];
    float v[8];
    float mx = 0.f;
#pragma unroll
    for (int r = 0; r < 8; ++r) {
        int m = r * 256 + tid;
        const float4* Er = (const float4*)(E + (size_t)m * 16);
        float4 a = Er[0], b = Er[1], c = Er[2], d4 = Er[3];
        float s = 0.f;
        s = fmaf(a.x, e[0], s);  s = fmaf(a.y, e[1], s);
        s = fmaf(a.z, e[2], s);  s = fmaf(a.w, e[3], s);
        s = fmaf(b.x, e[4], s);  s = fmaf(b.y, e[5], s);
        s = fmaf(b.z, e[6], s);  s = fmaf(b.w, e[7], s);
        s = fmaf(c.x, e[8], s);  s = fmaf(c.y, e[9], s);
        s = fmaf(c.z, e[10], s); s = fmaf(c.w, e[11], s);
        s = fmaf(d4.x, e[12], s); s = fmaf(d4.y, e[13], s);
        s = fmaf(d4.z, e[14], s); s = fmaf(d4.w, e[15], s);
        s = fmaxf(s, 0.f);                 // relu
        v[r] = s;
        mx = fmaxf(mx, s);
    }
    for (int off = 32; off; off >>= 1) mx = fmaxf(mx, __shfl_down(mx, off, 64));
    if (lane == 0) red[wave] = mx;
    __syncthreads();
    mx = fmaxf(fmaxf(red[0], red[1]), fmaxf(red[2], red[3]));
    __syncthreads();
    float sum = 0.f;
#pragma unroll
    for (int r = 0; r < 8; ++r) { v[r] = __expf(v[r] - mx); sum += v[r]; }
    for (int off = 32; off; off >>= 1) sum += __shfl_down(sum, off, 64);
    if (lane == 0) red[wave] = sum;
    __syncthreads();
    sum = red[0] + red[1] + red[2] + red[3];
    float inv = 1.f / sum;
#pragma unroll
    for (int r = 0; r < 8; ++r)
        Acat[(size_t)n * 4096 + r * 256 + tid] = f2bf(v[r] * inv);
}

// ---------------------------------------------------------------- casts
__global__ __launch_bounds__(256)
void cast_adj(const float* __restrict__ adj, u16* __restrict__ Acat) {
    size_t j = ((size_t)blockIdx.x * 256 + threadIdx.x) * 4;
    float4 v = *(const float4*)(adj + j);
    int n = (int)(j >> 11), c = (int)(j & 2047);
    ushort4 o = make_ushort4(f2bf(v.x), f2bf(v.y), f2bf(v.z), f2bf(v.w));
    *(ushort4*)(Acat + (size_t)n * 4096 + 2048 + c) = o;
}

__global__ __launch_bounds__(256)
void cast_bf16_vec(const float* __restrict__ in, u16* __restrict__ out) {
    size_t j = ((size_t)blockIdx.x * 256 + threadIdx.x) * 4;
    float4 v = *(const float4*)(in + j);
    ushort4 o = make_ushort4(f2bf(v.x), f2bf(v.y), f2bf(v.z), f2bf(v.w));
    *(ushort4*)(out + j) = o;
}

// ---------------------------------------------------------------- transposes
__global__ __launch_bounds__(256)
void transpose_bf16(const u16* __restrict__ in, u16* __restrict__ out) {
    __shared__ u16 t[64][65];
    int bx = blockIdx.x * 64, by = blockIdx.y * 64;
    int c = threadIdx.x & 63, g = threadIdx.x >> 6;
#pragma unroll
    for (int r = 0; r < 16; ++r) {
        int row = g * 16 + r;
        t[row][c] = in[(size_t)(by + row) * 2048 + bx + c];
    }
    __syncthreads();
#pragma unroll
    for (int r = 0; r < 16; ++r) {
        int row = g * 16 + r;
        out[(size_t)(bx + row) * 2048 + by + c] = t[c][row];
    }
}

// x[b,m,c] -> XtT[(b*64+c)][m]  (bf16)
__global__ __launch_bounds__(256)
void build_xtT(const float* __restrict__ x, u16* __restrict__ xtT) {
    __shared__ u16 t[64][65];
    int b = blockIdx.y, m0 = blockIdx.x * 64;
    int c = threadIdx.x & 63, g = threadIdx.x >> 6;
#pragma unroll
    for (int r = 0; r < 16; ++r) {
        int mm = g * 16 + r;
        t[mm][c] = f2bf(x[((size_t)b * 2048 + m0 + mm) * 64 + c]);
    }
    __syncthreads();
#pragma unroll
    for (int r = 0; r < 16; ++r) {
        int cc = g * 16 + r;
        xtT[((size_t)b * 64 + cc) * 2048 + m0 + c] = t[c][cc];
    }
}

// ---------------------------------------------------------------- GEMM (m97 style, Bt operand)
// C[m,n] = sum_k A[m,k] * Bt[n,k].  M,N mult of 128, K mult of 32.
// MODE 0: store fp32 C.  MODE 1: fused sigmoid blend -> S_bf.  MODE 2: T2 = 2C - I -> bf16.
template <int MODE>
__global__ __launch_bounds__(256)
void gemm_bt(const u16* __restrict__ A, const u16* __restrict__ Bt,
             float* __restrict__ Cf, u16* __restrict__ Cb,
             const float* __restrict__ adj, const u16* __restrict__ sup,
             int M, int N, int K) {
    __shared__ alignas(16) u16 As[128 * 32];
    __shared__ alignas(16) u16 Bs[128 * 32];
    const int tid = threadIdx.x, lane = tid & 63, wave = tid >> 6;
    const int m0 = blockIdx.y * 128, n0 = blockIdx.x * 128;
    const int wm = (wave >> 1) * 64, wn = (wave & 1) * 64;
    f32x4 acc[4][4] = {};

    for (int k0 = 0; k0 < K; k0 += 32) {
#pragma unroll
        for (int r = 0; r < 2; ++r) {
            int q = wave * 64 + r * 256 + lane;        // chunk id 0..511
            int row = q >> 2, col = (q & 3) * 8;
            u16* ldsA = As + (wave * 64 + r * 256) * 8;    // wave-uniform base
            u16* ldsB = Bs + (wave * 64 + r * 256) * 8;
            gl_lds16(A + (size_t)(m0 + row) * K + k0 + col, ldsA);
            gl_lds16(Bt + (size_t)(n0 + row) * K + k0 + col, ldsB);
        }
        __syncthreads();
        const int kl = (lane >> 4) * 8;
        const int ml = lane & 15;
        bf16x8 af[4], bfv[4];
#pragma unroll
        for (int i = 0; i < 4; ++i) {
            af[i]  = *(const bf16x8*)(As + (wm + i * 16 + ml) * 32 + kl);
            bfv[i] = *(const bf16x8*)(Bs + (wn + i * 16 + ml) * 32 + kl);
        }
#pragma unroll
        for (int i = 0; i < 4; ++i)
#pragma unroll
            for (int j = 0; j < 4; ++j)
                acc[i][j] = __builtin_amdgcn_mfma_f32_16x16x32_bf16(af[i], bfv[j], acc[i][j], 0, 0, 0);
        __syncthreads();
    }

    const int col_l = lane & 15, row_l = (lane >> 4) * 4;
#pragma unroll
    for (int i = 0; i < 4; ++i)
#pragma unroll
        for (int j = 0; j < 4; ++j)
#pragma unroll
            for (int r = 0; r < 4; ++r) {
                int row = m0 + wm + i * 16 + row_l + r;
                int col = n0 + wn + j * 16 + col_l;
                float v = acc[i][j][r];
                if (MODE == 0) {
                    Cf[(size_t)row * N + col] = v;
                } else if (MODE == 1) {
                    float s2 = 1.f / (1.f + __expf(-v));
                    float av = adj[(size_t)row * N + col];
                    float sv = bf2f(sup[(size_t)row * 4096 + col]);
                    Cb[(size_t)row * N + col] = f2bf(s2 * av + (1.f - s2) * sv);
                } else {
                    Cb[(size_t)row * N + col] = f2bf(2.f * v - (row == col ? 1.f : 0.f));
                }
            }
}

// ---------------------------------------------------------------- final gconv
__global__ __launch_bounds__(256)
void gconv(const float* __restrict__ x, const float* __restrict__ E,
           const float* __restrict__ Wp, const float* __restrict__ bp,
           const float* __restrict__ xg1, const float* __restrict__ xg2,
           float* __restrict__ out) {
    const int n = blockIdx.x, tid = threadIdx.x;
    __shared__ alignas(16) u16 wl[3 * 64 * 64];     // bf16 weights [k][i][o], 24 KB
    __shared__ alignas(16) float xl[3 * 32 * 68];   // padded (stride 68) x_g rows, ~26 KB
    __shared__ float bl[64];
    float e[16];
#pragma unroll
    for (int d = 0; d < 16; ++d) e[d] = E[n * 16 + d];
    // per-node weights: wl[idx] = sum_d e[d] * Wp[d*12288 + idx]
    for (int idx = tid; idx < 12288; idx += 256) {
        float s = 0.f;
#pragma unroll
        for (int d = 0; d < 16; ++d) s = fmaf(e[d], Wp[(size_t)d * 12288 + idx], s);
        wl[idx] = f2bf(s);
    }
    if (tid < 64) {
        float s = 0.f;
#pragma unroll
        for (int d = 0; d < 16; ++d) s = fmaf(e[d], bp[d * 64 + tid], s);
        bl[tid] = s;
    }
    // stage x_g rows: k=0 from x, k=1/2 from xg1/xg2
    for (int j4 = tid; j4 < 512; j4 += 256) {
        int j = j4 * 4, b = j >> 6, i = j & 63;
        int lo = b * 68 + i;
        *(float4*)(xl + lo)        = *(const float4*)(x   + ((size_t)b * 2048 + n) * 64 + i);
        *(float4*)(xl + 2176 + lo) = *(const float4*)(xg1 + (size_t)n * 2048 + j);
        *(float4*)(xl + 4352 + lo) = *(const float4*)(xg2 + (size_t)n * 2048 + j);
    }
    __syncthreads();
    const int b = tid >> 3, og = tid & 7;
    float acc[8];
#pragma unroll
    for (int t = 0; t < 8; ++t) acc[t] = bl[og * 8 + t];
    for (int k = 0; k < 3; ++k) {
#pragma unroll 4
        for (int i = 0; i < 64; ++i) {
            float xv = xl[k * 2176 + b * 68 + i];
            u16x8 w = *(const u16x8*)(wl + (k * 64 + i) * 64 + og * 8);
#pragma unroll
            for (int t = 0; t < 8; ++t)
                acc[t] = fmaf(bf2f(w[t]), xv, acc[t]);
        }
    }
    float* op = out + ((size_t)b * 2048 + n) * 64 + og * 8;
    *(float4*)op       = make_float4(acc[0], acc[1], acc[2], acc[3]);
    *((float4*)op + 1) = make_float4(acc[4], acc[5], acc[6], acc[7]);
}

// ---------------------------------------------------------------- launch
extern "C" void kernel_launch(void* const* d_in, const int* in_sizes, int n_in,
                              void* d_out, int out_size, void* d_ws, size_t ws_size,
                              hipStream_t stream) {
    const float* x   = (const float*)d_in[0];   // [32,2048,64]
    const float* E   = (const float*)d_in[1];   // [2048,16]
    const float* adj = (const float*)d_in[2];   // [2048,2048]
    const float* Wp  = (const float*)d_in[3];   // [16,3,64,64]
    const float* bp  = (const float*)d_in[4];   // [16,64]
    const float* saw = (const float*)d_in[5];   // [2048,4096]
    float* out = (float*)d_out;

    char* ws = (char*)d_ws;
    u16*  Acat  = (u16*)(ws);                       // 16 MB  [2048][4096] bf16
    u16*  sawb  = (u16*)(ws + (16u << 20));         // 16 MB  [2048][4096] bf16
    u16*  XtT   = (u16*)(ws + (32u << 20));         //  8 MB  [2048][2048] bf16
    u16*  S_bf  = (u16*)(ws + (40u << 20));         //  8 MB
    float* xg1  = (float*)(ws + (48u << 20));       // 16 MB  [2048][2048] f32
    float* xg2  = (float*)(ws + (64u << 20));       // 16 MB
    u16*  St_bf = Acat;                             // alias: Acat dead after gemm<1>
    u16*  T2_bf = sawb;                             // alias: sawb dead after gemm<1>

    supports_softmax<<<2048, 256, 0, stream>>>(E, Acat);
    cast_adj<<<4096, 256, 0, stream>>>(adj, Acat);
    cast_bf16_vec<<<8192, 256, 0, stream>>>(saw, sawb);
    build_xtT<<<dim3(32, 32), 256, 0, stream>>>(x, XtT);

    // z GEMM + fused sigmoid blend -> S_bf
    gemm_bt<1><<<dim3(16, 16), 256, 0, stream>>>(Acat, sawb, nullptr, S_bf, adj, Acat,
                                                 2048, 2048, 4096);
    transpose_bf16<<<dim3(32, 32), 256, 0, stream>>>(S_bf, St_bf);
    // T2 = 2*S@S - I
    gemm_bt<2><<<dim3(16, 16), 256, 0, stream>>>(S_bf, St_bf, nullptr, T2_bf, nullptr, nullptr,
                                                 2048, 2048, 2048);
    // xg1 = S @ Xt, xg2 = T2 @ Xt
    gemm_bt<0><<<dim3(16, 16), 256, 0, stream>>>(S_bf, XtT, xg1, nullptr, nullptr, nullptr,
                                                 2048, 2048, 2048);
    gemm_bt<0><<<dim3(16, 16), 256, 0, stream>>>(T2_bf, XtT, xg2, nullptr, nullptr, nullptr,
                                                 2048, 2048, 2048);

    gconv<<<2048, 256, 0, stream>>>(x, E, Wp, bp, xg1, xg2, out);
}

// Round 2
// 372.737 us; speedup vs baseline: 1.2755x; 1.2755x over previous
//
#include <hip/hip_runtime.h>

// AVWGCN: B=32, N=2048, C=64, O=64, K=3, D=16
// R2 changes vs R1:
//  - gconv split: wgen GEMM materializes Wn = E @ Wp_flat as [2048][12288] bf16 (50 MB,
//    HBM-streamed) -> gconv streams 24 KB/node instead of re-reading 786 KB Wp from L2
//    per block (was 1.6 GB L2 traffic + 0.8 GF redundant VALU -> 122 us).
//  - GEMMs: BN templated; 128x64 tiles -> grid 512/1024 blocks (8-16 waves/CU vs 4).
//  - xg1+xg2 fused into one M=4096 GEMM (A = [S;T2] contiguous).
// Workspace map (peak 82.3 MB):
//  phase 1: Acat 0..16M | sawb 16..32M | XtT 32..40M | S 40..48M | T2 48..56M | St alias Acat
//  phase 2 (after xg GEMM): xg fp32 0..32M | Wn bf16 32..82.3M (XtT/S/T2 dead)

typedef unsigned short u16;
typedef float f32x4 __attribute__((ext_vector_type(4)));
typedef __bf16 bf16x8 __attribute__((ext_vector_type(8)));
typedef unsigned short u16x8 __attribute__((ext_vector_type(8)));

__device__ __forceinline__ u16 f2bf(float f) {
    unsigned u = __float_as_uint(f);
    u += 0x7FFFu + ((u >> 16) & 1u);   // RNE
    return (u16)(u >> 16);
}
__device__ __forceinline__ float bf2f(u16 h) {
    return __uint_as_float((unsigned)h << 16);
}
__device__ __forceinline__ void gl_lds16(const void* g, void* l) {
    __builtin_amdgcn_global_load_lds(
        (const __attribute__((address_space(1))) unsigned*)g,
        (__attribute__((address_space(3))) unsigned*)l, 16, 0, 0);
}

// ---------------------------------------------------------------- supports
__global__ __launch_bounds__(256)
void supports_softmax(const float* __restrict__ E, u16* __restrict__ Acat) {
    const int n = blockIdx.x, tid = threadIdx.x;
    const int lane = tid & 63, wave = tid >> 6;
    __shared__ float red[4];
    float e[16];
#pragma unroll
    for (int d = 0; d < 16; ++d) e[d] = E[n * 16 + d];
    float v[8];
    float mx = 0.f;
#pragma unroll
    for (int r = 0; r < 8; ++r) {
        int m = r * 256 + tid;
        const float4* Er = (const float4*)(E + (size_t)m * 16);
        float4 a = Er[0], b = Er[1], c = Er[2], d4 = Er[3];
        float s = 0.f;
        s = fmaf(a.x, e[0], s);  s = fmaf(a.y, e[1], s);
        s = fmaf(a.z, e[2], s);  s = fmaf(a.w, e[3], s);
        s = fmaf(b.x, e[4], s);  s = fmaf(b.y, e[5], s);
        s = fmaf(b.z, e[6], s);  s = fmaf(b.w, e[7], s);
        s = fmaf(c.x, e[8], s);  s = fmaf(c.y, e[9], s);
        s = fmaf(c.z, e[10], s); s = fmaf(c.w, e[11], s);
        s = fmaf(d4.x, e[12], s); s = fmaf(d4.y, e[13], s);
        s = fmaf(d4.z, e[14], s); s = fmaf(d4.w, e[15], s);
        s = fmaxf(s, 0.f);                 // relu
        v[r] = s;
        mx = fmaxf(mx, s);
    }
    for (int off = 32; off; off >>= 1) mx = fmaxf(mx, __shfl_down(mx, off, 64));
    if (lane == 0) red[wave] = mx;
    __syncthreads();
    mx = fmaxf(fmaxf(red[0], red[1]), fmaxf(red[2], red[3]));
    __syncthreads();
    float sum = 0.f;
#pragma unroll
    for (int r = 0; r < 8; ++r) { v[r] = __expf(v[r] - mx); sum += v[r]; }
    for (int off = 32; off; off >>= 1) sum += __shfl_down(sum, off, 64);
    if (lane == 0) red[wave] = sum;
    __syncthreads();
    sum = red[0] + red[1] + red[2] + red[3];
    float inv = 1.f / sum;
#pragma unroll
    for (int r = 0; r < 8; ++r)
        Acat[(size_t)n * 4096 + r * 256 + tid] = f2bf(v[r] * inv);
}

// ---------------------------------------------------------------- casts
__global__ __launch_bounds__(256)
void cast_adj(const float* __restrict__ adj, u16* __restrict__ Acat) {
    size_t j = ((size_t)blockIdx.x * 256 + threadIdx.x) * 4;
    float4 v = *(const float4*)(adj + j);
    int n = (int)(j >> 11), c = (int)(j & 2047);
    ushort4 o = make_ushort4(f2bf(v.x), f2bf(v.y), f2bf(v.z), f2bf(v.w));
    *(ushort4*)(Acat + (size_t)n * 4096 + 2048 + c) = o;
}

__global__ __launch_bounds__(256)
void cast_bf16_vec(const float* __restrict__ in, u16* __restrict__ out) {
    size_t j = ((size_t)blockIdx.x * 256 + threadIdx.x) * 4;
    float4 v = *(const float4*)(in + j);
    ushort4 o = make_ushort4(f2bf(v.x), f2bf(v.y), f2bf(v.z), f2bf(v.w));
    *(ushort4*)(out + j) = o;
}

// ---------------------------------------------------------------- transposes
__global__ __launch_bounds__(256)
void transpose_bf16(const u16* __restrict__ in, u16* __restrict__ out) {
    __shared__ u16 t[64][65];
    int bx = blockIdx.x * 64, by = blockIdx.y * 64;
    int c = threadIdx.x & 63, g = threadIdx.x >> 6;
#pragma unroll
    for (int r = 0; r < 16; ++r) {
        int row = g * 16 + r;
        t[row][c] = in[(size_t)(by + row) * 2048 + bx + c];
    }
    __syncthreads();
#pragma unroll
    for (int r = 0; r < 16; ++r) {
        int row = g * 16 + r;
        out[(size_t)(bx + row) * 2048 + by + c] = t[c][row];
    }
}

// x[b,m,c] -> XtT[(b*64+c)][m]  (bf16)
__global__ __launch_bounds__(256)
void build_xtT(const float* __restrict__ x, u16* __restrict__ xtT) {
    __shared__ u16 t[64][65];
    int b = blockIdx.y, m0 = blockIdx.x * 64;
    int c = threadIdx.x & 63, g = threadIdx.x >> 6;
#pragma unroll
    for (int r = 0; r < 16; ++r) {
        int mm = g * 16 + r;
        t[mm][c] = f2bf(x[((size_t)b * 2048 + m0 + mm) * 64 + c]);
    }
    __syncthreads();
#pragma unroll
    for (int r = 0; r < 16; ++r) {
        int cc = g * 16 + r;
        xtT[((size_t)b * 64 + cc) * 2048 + m0 + c] = t[c][cc];
    }
}

// ---------------------------------------------------------------- GEMM (m97 style, Bt operand)
// C[m,n] = sum_k A[m,k] * Bt[n,k].  Tile BM=128 x BN, BK=32.
// MODE 0: fp32 C.  MODE 1: fused sigmoid blend -> bf16.  MODE 2: T2 = 2C - I -> bf16.
template <int MODE, int BN>
__global__ __launch_bounds__(256)
void gemm_bt(const u16* __restrict__ A, const u16* __restrict__ Bt,
             float* __restrict__ Cf, u16* __restrict__ Cb,
             const float* __restrict__ adj, const u16* __restrict__ sup,
             int M, int N, int K) {
    constexpr int NJ = BN / 32;          // 16-col j-tiles per wave
    __shared__ alignas(16) u16 As[128 * 32];
    __shared__ alignas(16) u16 Bs[BN * 32];
    const int tid = threadIdx.x, lane = tid & 63, wave = tid >> 6;
    const int m0 = blockIdx.y * 128, n0 = blockIdx.x * BN;
    const int wm = (wave >> 1) * 64, wn = (wave & 1) * (BN / 2);
    f32x4 acc[4][NJ] = {};

    for (int k0 = 0; k0 < K; k0 += 32) {
#pragma unroll
        for (int r = 0; r < 2; ++r) {           // A: 512 16B-chunks
            int q = wave * 64 + r * 256 + lane;
            int row = q >> 2, col = (q & 3) * 8;
            u16* ldsA = As + (wave * 64 + r * 256) * 8;   // wave-uniform base
            gl_lds16(A + (size_t)(m0 + row) * K + k0 + col, ldsA);
        }
#pragma unroll
        for (int r = 0; r < BN / 64; ++r) {     // B: BN*4 16B-chunks
            int q = wave * 64 + r * 256 + lane;
            int row = q >> 2, col = (q & 3) * 8;
            u16* ldsB = Bs + (wave * 64 + r * 256) * 8;
            gl_lds16(Bt + (size_t)(n0 + row) * K + k0 + col, ldsB);
        }
        __syncthreads();
        const int kl = (lane >> 4) * 8;
        const int ml = lane & 15;
        bf16x8 af[4], bfv[NJ];
#pragma unroll
        for (int i = 0; i < 4; ++i)
            af[i]  = *(const bf16x8*)(As + (wm + i * 16 + ml) * 32 + kl);
#pragma unroll
        for (int j = 0; j < NJ; ++j)
            bfv[j] = *(const bf16x8*)(Bs + (wn + j * 16 + ml) * 32 + kl);
#pragma unroll
        for (int i = 0; i < 4; ++i)
#pragma unroll
            for (int j = 0; j < NJ; ++j)
                acc[i][j] = __builtin_amdgcn_mfma_f32_16x16x32_bf16(af[i], bfv[j], acc[i][j], 0, 0, 0);
        __syncthreads();
    }

    const int col_l = lane & 15, row_l = (lane >> 4) * 4;
#pragma unroll
    for (int i = 0; i < 4; ++i)
#pragma unroll
        for (int j = 0; j < NJ; ++j)
#pragma unroll
            for (int r = 0; r < 4; ++r) {
                int row = m0 + wm + i * 16 + row_l + r;
                int col = n0 + wn + j * 16 + col_l;
                float v = acc[i][j][r];
                if (MODE == 0) {
                    Cf[(size_t)row * N + col] = v;
                } else if (MODE == 1) {
                    float s2 = 1.f / (1.f + __expf(-v));
                    float av = adj[(size_t)row * N + col];
                    float sv = bf2f(sup[(size_t)row * 4096 + col]);
                    Cb[(size_t)row * N + col] = f2bf(s2 * av + (1.f - s2) * sv);
                } else {
                    Cb[(size_t)row * N + col] = f2bf(2.f * v - (row == col ? 1.f : 0.f));
                }
            }
}

// ---------------------------------------------------------------- wgen: Wn[n][kio] = sum_d E[n,d] Wp[d][kio]
// grid (12288/512, 2048/128); per block: 512-idx chunk x 128 n. Wp chunk held in regs.
__global__ __launch_bounds__(256)
void wgen(const float* __restrict__ E, const float* __restrict__ Wp,
          u16* __restrict__ Wn) {
    __shared__ float Es[128 * 16];
    const int tid = threadIdx.x;
    const int c0 = blockIdx.x * 512, nb = blockIdx.y * 128;
    const int i4 = (tid & 127) * 4, ng = tid >> 7;
    for (int j = tid; j < 2048; j += 256) Es[j] = E[nb * 16 + j];
    float4 wpv[16];
#pragma unroll
    for (int d = 0; d < 16; ++d)
        wpv[d] = *(const float4*)(Wp + (size_t)d * 12288 + c0 + i4);
    __syncthreads();
    for (int nl = 0; nl < 64; ++nl) {
        int n = ng * 64 + nl;
        float4 s = make_float4(0.f, 0.f, 0.f, 0.f);
#pragma unroll
        for (int d = 0; d < 16; ++d) {
            float e = Es[n * 16 + d];
            s.x = fmaf(e, wpv[d].x, s.x);
            s.y = fmaf(e, wpv[d].y, s.y);
            s.z = fmaf(e, wpv[d].z, s.z);
            s.w = fmaf(e, wpv[d].w, s.w);
        }
        ushort4 o = make_ushort4(f2bf(s.x), f2bf(s.y), f2bf(s.z), f2bf(s.w));
        *(ushort4*)(Wn + (size_t)(nb + n) * 12288 + c0 + i4) = o;
    }
}

// ---------------------------------------------------------------- final gconv (streams Wn)
__global__ __launch_bounds__(256)
void gconv(const float* __restrict__ x, const float* __restrict__ E,
           const u16* __restrict__ Wn, const float* __restrict__ bp,
           const float* __restrict__ xg1, const float* __restrict__ xg2,
           float* __restrict__ out) {
    const int n = blockIdx.x, tid = threadIdx.x;
    __shared__ alignas(16) float wl[3 * 64 * 64];   // 48 KB fp32 (converted once at load)
    __shared__ alignas(16) float xl[3 * 32 * 68];   // padded x_g rows, 26 KB
    __shared__ float bl[64];
    // stream this node's weights: 12288 bf16, convert to fp32 in LDS
    for (int j = tid * 8; j < 12288; j += 2048) {
        u16x8 w = *(const u16x8*)(Wn + (size_t)n * 12288 + j);
#pragma unroll
        for (int t = 0; t < 8; ++t) wl[j + t] = bf2f(w[t]);
    }
    if (tid < 64) {
        float s = 0.f;
#pragma unroll
        for (int d = 0; d < 16; ++d) s = fmaf(E[n * 16 + d], bp[d * 64 + tid], s);
        bl[tid] = s;
    }
    // stage x_g rows: k=0 from x, k=1/2 from xg1/xg2
    for (int j4 = tid; j4 < 512; j4 += 256) {
        int j = j4 * 4, b = j >> 6, i = j & 63;
        int lo = b * 68 + i;
        *(float4*)(xl + lo)        = *(const float4*)(x   + ((size_t)b * 2048 + n) * 64 + i);
        *(float4*)(xl + 2176 + lo) = *(const float4*)(xg1 + (size_t)n * 2048 + j);
        *(float4*)(xl + 4352 + lo) = *(const float4*)(xg2 + (size_t)n * 2048 + j);
    }
    __syncthreads();
    const int b = tid >> 3, og = tid & 7;
    float acc[8];
#pragma unroll
    for (int t = 0; t < 8; ++t) acc[t] = bl[og * 8 + t];
    for (int k = 0; k < 3; ++k) {
#pragma unroll 4
        for (int i = 0; i < 64; ++i) {
            float xv = xl[k * 2176 + b * 68 + i];
            const float4 w0 = *(const float4*)(wl + (k * 64 + i) * 64 + og * 8);
            const float4 w1 = *(const float4*)(wl + (k * 64 + i) * 64 + og * 8 + 4);
            acc[0] = fmaf(w0.x, xv, acc[0]); acc[1] = fmaf(w0.y, xv, acc[1]);
            acc[2] = fmaf(w0.z, xv, acc[2]); acc[3] = fmaf(w0.w, xv, acc[3]);
            acc[4] = fmaf(w1.x, xv, acc[4]); acc[5] = fmaf(w1.y, xv, acc[5]);
            acc[6] = fmaf(w1.z, xv, acc[6]); acc[7] = fmaf(w1.w, xv, acc[7]);
        }
    }
    float* op = out + ((size_t)b * 2048 + n) * 64 + og * 8;
    *(float4*)op       = make_float4(acc[0], acc[1], acc[2], acc[3]);
    *((float4*)op + 1) = make_float4(acc[4], acc[5], acc[6], acc[7]);
}

// ---------------------------------------------------------------- launch
extern "C" void kernel_launch(void* const* d_in, const int* in_sizes, int n_in,
                              void* d_out, int out_size, void* d_ws, size_t ws_size,
                              hipStream_t stream) {
    const float* x   = (const float*)d_in[0];   // [32,2048,64]
    const float* E   = (const float*)d_in[1];   // [2048,16]
    const float* adj = (const float*)d_in[2];   // [2048,2048]
    const float* Wp  = (const float*)d_in[3];   // [16,3,64,64]
    const float* bp  = (const float*)d_in[4];   // [16,64]
    const float* saw = (const float*)d_in[5];   // [2048,4096]
    float* out = (float*)d_out;

    char* ws = (char*)d_ws;
    u16*  Acat  = (u16*)(ws);                       // 16 MB  [2048][4096] bf16
    u16*  sawb  = (u16*)(ws + (16u << 20));         // 16 MB  [2048][4096] bf16
    u16*  XtT   = (u16*)(ws + (32u << 20));         //  8 MB  [2048][2048] bf16
    u16*  S_bf  = (u16*)(ws + (40u << 20));         //  8 MB
    u16*  T2_bf = (u16*)(ws + (48u << 20));         //  8 MB (contiguous after S: A=[S;T2])
    u16*  St_bf = Acat;                             // alias: Acat dead after gemm<1>
    float* xg   = (float*)(ws);                     // 32 MB: aliases Acat+sawb (dead)
    float* xg1  = xg;
    float* xg2  = xg + (size_t)2048 * 2048;
    u16*  Wn    = (u16*)(ws + (32u << 20));         // 50.3 MB: aliases XtT+S+T2 (dead)

    supports_softmax<<<2048, 256, 0, stream>>>(E, Acat);
    cast_adj<<<4096, 256, 0, stream>>>(adj, Acat);
    cast_bf16_vec<<<8192, 256, 0, stream>>>(saw, sawb);
    build_xtT<<<dim3(32, 32), 256, 0, stream>>>(x, XtT);

    // z GEMM + fused sigmoid blend -> S_bf   (grid 32x16 = 512 blocks)
    gemm_bt<1, 64><<<dim3(32, 16), 256, 0, stream>>>(Acat, sawb, nullptr, S_bf, adj, Acat,
                                                     2048, 2048, 4096);
    transpose_bf16<<<dim3(32, 32), 256, 0, stream>>>(S_bf, St_bf);
    // T2 = 2*S@S - I                          (grid 32x16 = 512 blocks)
    gemm_bt<2, 64><<<dim3(32, 16), 256, 0, stream>>>(S_bf, St_bf, nullptr, T2_bf, nullptr, nullptr,
                                                     2048, 2048, 2048);
    // merged: [xg1; xg2] = [S; T2] @ Xt^T     (grid 32x32 = 1024 blocks)
    gemm_bt<0, 64><<<dim3(32, 32), 256, 0, stream>>>(S_bf, XtT, xg, nullptr, nullptr, nullptr,
                                                     4096, 2048, 2048);
    // materialize per-node weights (bf16)
    wgen<<<dim3(24, 16), 256, 0, stream>>>(E, Wp, Wn);

    gconv<<<2048, 256, 0, stream>>>(x, E, Wn, bp, xg1, xg2, out);
}

// Round 3
// 337.035 us; speedup vs baseline: 1.4106x; 1.1059x over previous
//
#include <hip/hip_runtime.h>

// AVWGCN: B=32, N=2048, C=64, O=64, K=3, D=16
// R3 changes vs R2 (z-GEMM was MfmaUtil 15 / VALUBusy 17 / Occ 22 -> barrier/latency bound):
//  - Split-K=2 on z and T2 GEMMs: grid 512 -> 1024 blocks (4 blocks/CU, occupancy cap 50%).
//    fp32 partials + streaming reduce kernels carrying the old epilogues (sigmoid-blend, 2C-I).
//  - BK=64: 16 MFMAs per barrier pair (2x fewer barriers). Row stride 128B == 32 banks would
//    be 16-way conflicted, so chunk XOR swizzle (slot = c ^ (row&7)) -> 2-way max (free).
//  - xg GEMM stores bf16 directly; gconv reads bf16 xg.
// Workspace map (peak 80 MiB), phases:
//  [0,16M) Acat -> then S_bf [0,8M) + T2_bf [8,16M) -> then Wn [0,50.3M)
//  [16,32M) sawb -> then St [16,24M)
//  [32,40M) XtT   [40,48M) supC   [48,80M) zpart/T2part -> xg_bf [56,72M)

typedef unsigned short u16;
typedef float f32x4 __attribute__((ext_vector_type(4)));
typedef __bf16 bf16x8 __attribute__((ext_vector_type(8)));
typedef unsigned short u16x8 __attribute__((ext_vector_type(8)));

__device__ __forceinline__ u16 f2bf(float f) {
    unsigned u = __float_as_uint(f);
    u += 0x7FFFu + ((u >> 16) & 1u);   // RNE
    return (u16)(u >> 16);
}
__device__ __forceinline__ float bf2f(u16 h) {
    return __uint_as_float((unsigned)h << 16);
}
__device__ __forceinline__ void gl_lds16(const void* g, void* l) {
    __builtin_amdgcn_global_load_lds(
        (const __attribute__((address_space(1))) unsigned*)g,
        (__attribute__((address_space(3))) unsigned*)l, 16, 0, 0);
}

// ---------------------------------------------------------------- supports
__global__ __launch_bounds__(256)
void supports_softmax(const float* __restrict__ E, u16* __restrict__ Acat,
                      u16* __restrict__ supC) {
    const int n = blockIdx.x, tid = threadIdx.x;
    const int lane = tid & 63, wave = tid >> 6;
    __shared__ float red[4];
    float e[16];
#pragma unroll
    for (int d = 0; d < 16; ++d) e[d] = E[n * 16 + d];
    float v[8];
    float mx = 0.f;
#pragma unroll
    for (int r = 0; r < 8; ++r) {
        int m = r * 256 + tid;
        const float4* Er = (const float4*)(E + (size_t)m * 16);
        float4 a = Er[0], b = Er[1], c = Er[2], d4 = Er[3];
        float s = 0.f;
        s = fmaf(a.x, e[0], s);  s = fmaf(a.y, e[1], s);
        s = fmaf(a.z, e[2], s);  s = fmaf(a.w, e[3], s);
        s = fmaf(b.x, e[4], s);  s = fmaf(b.y, e[5], s);
        s = fmaf(b.z, e[6], s);  s = fmaf(b.w, e[7], s);
        s = fmaf(c.x, e[8], s);  s = fmaf(c.y, e[9], s);
        s = fmaf(c.z, e[10], s); s = fmaf(c.w, e[11], s);
        s = fmaf(d4.x, e[12], s); s = fmaf(d4.y, e[13], s);
        s = fmaf(d4.z, e[14], s); s = fmaf(d4.w, e[15], s);
        s = fmaxf(s, 0.f);                 // relu
        v[r] = s;
        mx = fmaxf(mx, s);
    }
    for (int off = 32; off; off >>= 1) mx = fmaxf(mx, __shfl_down(mx, off, 64));
    if (lane == 0) red[wave] = mx;
    __syncthreads();
    mx = fmaxf(fmaxf(red[0], red[1]), fmaxf(red[2], red[3]));
    __syncthreads();
    float sum = 0.f;
#pragma unroll
    for (int r = 0; r < 8; ++r) { v[r] = __expf(v[r] - mx); sum += v[r]; }
    for (int off = 32; off; off >>= 1) sum += __shfl_down(sum, off, 64);
    if (lane == 0) red[wave] = sum;
    __syncthreads();
    sum = red[0] + red[1] + red[2] + red[3];
    float inv = 1.f / sum;
#pragma unroll
    for (int r = 0; r < 8; ++r) {
        u16 o = f2bf(v[r] * inv);
        Acat[(size_t)n * 4096 + r * 256 + tid] = o;
        supC[(size_t)n * 2048 + r * 256 + tid] = o;
    }
}

// ---------------------------------------------------------------- casts
__global__ __launch_bounds__(256)
void cast_adj(const float* __restrict__ adj, u16* __restrict__ Acat) {
    size_t j = ((size_t)blockIdx.x * 256 + threadIdx.x) * 4;
    float4 v = *(const float4*)(adj + j);
    int n = (int)(j >> 11), c = (int)(j & 2047);
    ushort4 o = make_ushort4(f2bf(v.x), f2bf(v.y), f2bf(v.z), f2bf(v.w));
    *(ushort4*)(Acat + (size_t)n * 4096 + 2048 + c) = o;
}

__global__ __launch_bounds__(256)
void cast_bf16_vec(const float* __restrict__ in, u16* __restrict__ out) {
    size_t j = ((size_t)blockIdx.x * 256 + threadIdx.x) * 4;
    float4 v = *(const float4*)(in + j);
    ushort4 o = make_ushort4(f2bf(v.x), f2bf(v.y), f2bf(v.z), f2bf(v.w));
    *(ushort4*)(out + j) = o;
}

// ---------------------------------------------------------------- transposes
__global__ __launch_bounds__(256)
void transpose_bf16(const u16* __restrict__ in, u16* __restrict__ out) {
    __shared__ u16 t[64][65];
    int bx = blockIdx.x * 64, by = blockIdx.y * 64;
    int c = threadIdx.x & 63, g = threadIdx.x >> 6;
#pragma unroll
    for (int r = 0; r < 16; ++r) {
        int row = g * 16 + r;
        t[row][c] = in[(size_t)(by + row) * 2048 + bx + c];
    }
    __syncthreads();
#pragma unroll
    for (int r = 0; r < 16; ++r) {
        int row = g * 16 + r;
        out[(size_t)(bx + row) * 2048 + by + c] = t[c][row];
    }
}

// x[b,m,c] -> XtT[(b*64+c)][m]  (bf16)
__global__ __launch_bounds__(256)
void build_xtT(const float* __restrict__ x, u16* __restrict__ xtT) {
    __shared__ u16 t[64][65];
    int b = blockIdx.y, m0 = blockIdx.x * 64;
    int c = threadIdx.x & 63, g = threadIdx.x >> 6;
#pragma unroll
    for (int r = 0; r < 16; ++r) {
        int mm = g * 16 + r;
        t[mm][c] = f2bf(x[((size_t)b * 2048 + m0 + mm) * 64 + c]);
    }
    __syncthreads();
#pragma unroll
    for (int r = 0; r < 16; ++r) {
        int cc = g * 16 + r;
        xtT[((size_t)b * 64 + cc) * 2048 + m0 + c] = t[c][cc];
    }
}

// ---------------------------------------------------------------- GEMM
// C[m,n] = sum_k A[m,k]*Bt[n,k]. BM=128, BN=64, BK=64, XOR-swizzled LDS.
// Split-K via gridDim.z (Kh = K/gridDim.z per z-slice).
// MODE 0: fp32 partial -> Cf + z*M*N.  MODE 3: bf16 -> Cb.
template <int MODE>
__global__ __launch_bounds__(256, 4)
void gemm_bt(const u16* __restrict__ A, const u16* __restrict__ Bt,
             float* __restrict__ Cf, u16* __restrict__ Cb,
             int M, int N, int K, int Kh) {
    __shared__ alignas(16) u16 As[128 * 64];   // 16 KB
    __shared__ alignas(16) u16 Bs[64 * 64];    //  8 KB
    const int tid = threadIdx.x, lane = tid & 63, wave = tid >> 6;
    const int m0 = blockIdx.y * 128, n0 = blockIdx.x * 64;
    const int wm = (wave >> 1) * 64, wn = (wave & 1) * 32;
    const int kbeg = blockIdx.z * Kh, kend = kbeg + Kh;
    const int ml = lane & 15, c0l = lane >> 4;       // frag row-in-tile, k-chunk
    f32x4 acc[4][2] = {};

    // fragment LDS slot precompute: chunk (row m, kchunk c) lives at slot m*8 + (c^(m&7))
    int baseA[4], mskA[4], baseB[2], mskB[2];
#pragma unroll
    for (int i = 0; i < 4; ++i) { int m = wm + i * 16 + ml; baseA[i] = m * 8; mskA[i] = m & 7; }
#pragma unroll
    for (int j = 0; j < 2; ++j) { int nn = wn + j * 16 + ml; baseB[j] = nn * 8; mskB[j] = nn & 7; }

    for (int k0 = kbeg; k0 < kend; k0 += 64) {
#pragma unroll
        for (int r = 0; r < 4; ++r) {           // A: 1024 16B-chunks
            int s = wave * 64 + r * 256 + lane;
            int row = s >> 3, gc = (s & 7) ^ (row & 7);
            u16* lds = As + (wave * 64 + r * 256) * 8;   // wave-uniform base
            gl_lds16(A + (size_t)(m0 + row) * K + k0 + gc * 8, lds);
        }
#pragma unroll
        for (int r = 0; r < 2; ++r) {           // B: 512 16B-chunks
            int s = wave * 64 + r * 256 + lane;
            int row = s >> 3, gc = (s & 7) ^ (row & 7);
            u16* lds = Bs + (wave * 64 + r * 256) * 8;
            gl_lds16(Bt + (size_t)(n0 + row) * K + k0 + gc * 8, lds);
        }
        __syncthreads();
#pragma unroll
        for (int ks8 = 0; ks8 < 8; ks8 += 4) {  // two K=32 sub-steps
            bf16x8 af[4], bv[2];
#pragma unroll
            for (int i = 0; i < 4; ++i)
                af[i] = *(const bf16x8*)(As + (baseA[i] + ((c0l + ks8) ^ mskA[i])) * 8);
#pragma unroll
            for (int j = 0; j < 2; ++j)
                bv[j] = *(const bf16x8*)(Bs + (baseB[j] + ((c0l + ks8) ^ mskB[j])) * 8);
#pragma unroll
            for (int i = 0; i < 4; ++i)
#pragma unroll
                for (int j = 0; j < 2; ++j)
                    acc[i][j] = __builtin_amdgcn_mfma_f32_16x16x32_bf16(af[i], bv[j], acc[i][j], 0, 0, 0);
        }
        __syncthreads();
    }

    const int col_l = lane & 15, row_l = (lane >> 4) * 4;
    float* Cfp = Cf + (size_t)blockIdx.z * M * N;
#pragma unroll
    for (int i = 0; i < 4; ++i)
#pragma unroll
        for (int j = 0; j < 2; ++j)
#pragma unroll
            for (int r = 0; r < 4; ++r) {
                int row = m0 + wm + i * 16 + row_l + r;
                int col = n0 + wn + j * 16 + col_l;
                if (MODE == 0) Cfp[(size_t)row * N + col] = acc[i][j][r];
                else           Cb[(size_t)row * N + col] = f2bf(acc[i][j][r]);
            }
}

// ---------------------------------------------------------------- split-K reduces (carry epilogues)
// S = sig(z)*adj + (1-sig(z))*sup,  z = p0+p1
__global__ __launch_bounds__(256)
void reduce_z(const float* __restrict__ p, const float* __restrict__ adj,
              const u16* __restrict__ supC, u16* __restrict__ S) {
    size_t j = ((size_t)blockIdx.x * 256 + threadIdx.x) * 4;
    float4 a = *(const float4*)(p + j);
    float4 b = *(const float4*)(p + (size_t)2048 * 2048 + j);
    float4 ad = *(const float4*)(adj + j);
    ushort4 sp = *(const ushort4*)(supC + j);
    float z0 = a.x + b.x, z1 = a.y + b.y, z2 = a.z + b.z, z3 = a.w + b.w;
    float s0 = 1.f / (1.f + __expf(-z0)), s1 = 1.f / (1.f + __expf(-z1));
    float s2 = 1.f / (1.f + __expf(-z2)), s3 = 1.f / (1.f + __expf(-z3));
    ushort4 o = make_ushort4(
        f2bf(s0 * ad.x + (1.f - s0) * bf2f(sp.x)),
        f2bf(s1 * ad.y + (1.f - s1) * bf2f(sp.y)),
        f2bf(s2 * ad.z + (1.f - s2) * bf2f(sp.z)),
        f2bf(s3 * ad.w + (1.f - s3) * bf2f(sp.w)));
    *(ushort4*)(S + j) = o;
}

// T2 = 2*(p0+p1) - I
__global__ __launch_bounds__(256)
void reduce_t2(const float* __restrict__ p, u16* __restrict__ T2) {
    size_t j = ((size_t)blockIdx.x * 256 + threadIdx.x) * 4;
    float4 a = *(const float4*)(p + j);
    float4 b = *(const float4*)(p + (size_t)2048 * 2048 + j);
    int row = (int)(j >> 11), col = (int)(j & 2047);
    float v[4] = {2.f * (a.x + b.x), 2.f * (a.y + b.y),
                  2.f * (a.z + b.z), 2.f * (a.w + b.w)};
#pragma unroll
    for (int t = 0; t < 4; ++t) if (row == col + t) v[t] -= 1.f;
    *(ushort4*)(T2 + j) = make_ushort4(f2bf(v[0]), f2bf(v[1]), f2bf(v[2]), f2bf(v[3]));
}

// ---------------------------------------------------------------- wgen: Wn[n][kio] = sum_d E[n,d] Wp[d][kio]
__global__ __launch_bounds__(256)
void wgen(const float* __restrict__ E, const float* __restrict__ Wp,
          u16* __restrict__ Wn) {
    __shared__ float Es[128 * 16];
    const int tid = threadIdx.x;
    const int c0 = blockIdx.x * 512, nb = blockIdx.y * 128;
    const int i4 = (tid & 127) * 4, ng = tid >> 7;
    for (int j = tid; j < 2048; j += 256) Es[j] = E[nb * 16 + j];
    float4 wpv[16];
#pragma unroll
    for (int d = 0; d < 16; ++d)
        wpv[d] = *(const float4*)(Wp + (size_t)d * 12288 + c0 + i4);
    __syncthreads();
    for (int nl = 0; nl < 64; ++nl) {
        int n = ng * 64 + nl;
        float4 s = make_float4(0.f, 0.f, 0.f, 0.f);
#pragma unroll
        for (int d = 0; d < 16; ++d) {
            float e = Es[n * 16 + d];
            s.x = fmaf(e, wpv[d].x, s.x);
            s.y = fmaf(e, wpv[d].y, s.y);
            s.z = fmaf(e, wpv[d].z, s.z);
            s.w = fmaf(e, wpv[d].w, s.w);
        }
        ushort4 o = make_ushort4(f2bf(s.x), f2bf(s.y), f2bf(s.z), f2bf(s.w));
        *(ushort4*)(Wn + (size_t)(nb + n) * 12288 + c0 + i4) = o;
    }
}

// ---------------------------------------------------------------- final gconv (streams Wn, bf16 xg)
__global__ __launch_bounds__(256)
void gconv(const float* __restrict__ x, const float* __restrict__ E,
           const u16* __restrict__ Wn, const float* __restrict__ bp,
           const u16* __restrict__ xg, float* __restrict__ out) {
    const int n = blockIdx.x, tid = threadIdx.x;
    __shared__ alignas(16) float wl[3 * 64 * 64];   // 48 KB fp32
    __shared__ alignas(16) float xl[3 * 32 * 68];   // padded x_g rows, 26 KB
    __shared__ float bl[64];
    for (int j = tid * 8; j < 12288; j += 2048) {
        u16x8 w = *(const u16x8*)(Wn + (size_t)n * 12288 + j);
#pragma unroll
        for (int t = 0; t < 8; ++t) wl[j + t] = bf2f(w[t]);
    }
    if (tid < 64) {
        float s = 0.f;
#pragma unroll
        for (int d = 0; d < 16; ++d) s = fmaf(E[n * 16 + d], bp[d * 64 + tid], s);
        bl[tid] = s;
    }
    for (int j4 = tid; j4 < 512; j4 += 256) {
        int j = j4 * 4, b = j >> 6, i = j & 63;
        int lo = b * 68 + i;
        *(float4*)(xl + lo) = *(const float4*)(x + ((size_t)b * 2048 + n) * 64 + i);
        ushort4 g1 = *(const ushort4*)(xg + (size_t)n * 2048 + j);
        ushort4 g2 = *(const ushort4*)(xg + (size_t)(2048 + n) * 2048 + j);
        *(float4*)(xl + 2176 + lo) = make_float4(bf2f(g1.x), bf2f(g1.y), bf2f(g1.z), bf2f(g1.w));
        *(float4*)(xl + 4352 + lo) = make_float4(bf2f(g2.x), bf2f(g2.y), bf2f(g2.z), bf2f(g2.w));
    }
    __syncthreads();
    const int b = tid >> 3, og = tid & 7;
    float acc[8];
#pragma unroll
    for (int t = 0; t < 8; ++t) acc[t] = bl[og * 8 + t];
    for (int k = 0; k < 3; ++k) {
#pragma unroll 4
        for (int i = 0; i < 64; ++i) {
            float xv = xl[k * 2176 + b * 68 + i];
            const float4 w0 = *(const float4*)(wl + (k * 64 + i) * 64 + og * 8);
            const float4 w1 = *(const float4*)(wl + (k * 64 + i) * 64 + og * 8 + 4);
            acc[0] = fmaf(w0.x, xv, acc[0]); acc[1] = fmaf(w0.y, xv, acc[1]);
            acc[2] = fmaf(w0.z, xv, acc[2]); acc[3] = fmaf(w0.w, xv, acc[3]);
            acc[4] = fmaf(w1.x, xv, acc[4]); acc[5] = fmaf(w1.y, xv, acc[5]);
            acc[6] = fmaf(w1.z, xv, acc[6]); acc[7] = fmaf(w1.w, xv, acc[7]);
        }
    }
    float* op = out + ((size_t)b * 2048 + n) * 64 + og * 8;
    *(float4*)op       = make_float4(acc[0], acc[1], acc[2], acc[3]);
    *((float4*)op + 1) = make_float4(acc[4], acc[5], acc[6], acc[7]);
}

// ---------------------------------------------------------------- launch
extern "C" void kernel_launch(void* const* d_in, const int* in_sizes, int n_in,
                              void* d_out, int out_size, void* d_ws, size_t ws_size,
                              hipStream_t stream) {
    const float* x   = (const float*)d_in[0];   // [32,2048,64]
    const float* E   = (const float*)d_in[1];   // [2048,16]
    const float* adj = (const float*)d_in[2];   // [2048,2048]
    const float* Wp  = (const float*)d_in[3];   // [16,3,64,64]
    const float* bp  = (const float*)d_in[4];   // [16,64]
    const float* saw = (const float*)d_in[5];   // [2048,4096]
    float* out = (float*)d_out;

    char* ws = (char*)d_ws;
    const size_t MB = 1u << 20;
    u16*   Acat  = (u16*)(ws);                  // [0,16M)
    u16*   sawb  = (u16*)(ws + 16 * MB);        // [16,32M)
    u16*   XtT   = (u16*)(ws + 32 * MB);        // [32,40M)
    u16*   supC  = (u16*)(ws + 40 * MB);        // [40,48M)
    float* zpart = (float*)(ws + 48 * MB);      // [48,80M) also T2part
    u16*   S_bf  = (u16*)(ws);                  // [0,8M)   after Acat dead
    u16*   T2_bf = (u16*)(ws + 8 * MB);         // [8,16M)  contiguous after S
    u16*   St    = (u16*)(ws + 16 * MB);        // [16,24M) after sawb dead
    u16*   xg_bf = (u16*)(ws + 56 * MB);        // [56,72M) after partials dead
    u16*   Wn    = (u16*)(ws);                  // [0,50.3M) after xg GEMM

    supports_softmax<<<2048, 256, 0, stream>>>(E, Acat, supC);
    cast_adj<<<4096, 256, 0, stream>>>(adj, Acat);
    cast_bf16_vec<<<8192, 256, 0, stream>>>(saw, sawb);
    build_xtT<<<dim3(32, 32), 256, 0, stream>>>(x, XtT);

    // z = Acat @ sawb^T (split-K=2, fp32 partials)
    gemm_bt<0><<<dim3(32, 16, 2), 256, 0, stream>>>(Acat, sawb, zpart, nullptr,
                                                    2048, 2048, 4096, 2048);
    reduce_z<<<4096, 256, 0, stream>>>(zpart, adj, supC, S_bf);
    transpose_bf16<<<dim3(32, 32), 256, 0, stream>>>(S_bf, St);
    // T2 partials = S @ S^T (split-K=2)
    gemm_bt<0><<<dim3(32, 16, 2), 256, 0, stream>>>(S_bf, St, zpart, nullptr,
                                                    2048, 2048, 2048, 1024);
    reduce_t2<<<4096, 256, 0, stream>>>(zpart, T2_bf);
    // [xg1; xg2] = [S; T2] @ XtT^T -> bf16
    gemm_bt<3><<<dim3(32, 32, 1), 256, 0, stream>>>(S_bf, XtT, nullptr, xg_bf,
                                                    4096, 2048, 2048, 2048);
    wgen<<<dim3(24, 16), 256, 0, stream>>>(E, Wp, Wn);
    gconv<<<2048, 256, 0, stream>>>(x, E, Wn, bp, xg_bf, out);
}

// Round 4
// 331.015 us; speedup vs baseline: 1.4362x; 1.0182x over previous
//
#include <hip/hip_runtime.h>

// AVWGCN: B=32, N=2048, C=64, O=64, K=3, D=16
// R4 changes vs R3:
//  - T2 GEMM eliminated algebraically: xg2 = (2*S@S - I)@X = 2*S@(S@X) - X.
//    G1 = S@X (17.2 GF), G2 = S@xg1 (17.2 GF); "2*" and "-X" folded into gconv weights
//    (W0' = W0-W2, W2' = 2*W2, k=2 stream is raw G2 output). Saves 17.2 GF + transpose.
//  - reduceT: split-K reduce of G1 fused with 64x64 tile transpose -> xg1 (for gconv)
//    and xg1T (Bt operand for G2).
//  - gconv: bf16 LDS for weights (24 KB) and x_g (13.5 KB) -> 38 KB -> 4 blocks/CU
//    (was 74 KB -> 2 blocks/CU, Occ 18%). bf2f in inner loop (VALUBusy was only 26%).
//  - supC dropped (reduce_z reads Acat left half); cast_adj+cast_saw fused. 11 kernels.
// Workspace (peak 80 MiB):
//  [0,16M) Acat -> xg1_bf [0,8M) + xg2_bf [8,16M)
//  [16,32M) sawb -> S [16,24M) + xg1T [24,32M) -> Wn [24,72M) after G2
//  [32,40M) XtT  |  [48,80M) split-K fp32 partials (z, G1, G2 sequentially)

typedef unsigned short u16;
typedef float f32x4 __attribute__((ext_vector_type(4)));
typedef __bf16 bf16x8 __attribute__((ext_vector_type(8)));
typedef unsigned short u16x8 __attribute__((ext_vector_type(8)));

__device__ __forceinline__ u16 f2bf(float f) {
    unsigned u = __float_as_uint(f);
    u += 0x7FFFu + ((u >> 16) & 1u);   // RNE
    return (u16)(u >> 16);
}
__device__ __forceinline__ float bf2f(u16 h) {
    return __uint_as_float((unsigned)h << 16);
}
__device__ __forceinline__ void gl_lds16(const void* g, void* l) {
    __builtin_amdgcn_global_load_lds(
        (const __attribute__((address_space(1))) unsigned*)g,
        (__attribute__((address_space(3))) unsigned*)l, 16, 0, 0);
}

// ---------------------------------------------------------------- supports
__global__ __launch_bounds__(256)
void supports_softmax(const float* __restrict__ E, u16* __restrict__ Acat) {
    const int n = blockIdx.x, tid = threadIdx.x;
    const int lane = tid & 63, wave = tid >> 6;
    __shared__ float red[4];
    float e[16];
#pragma unroll
    for (int d = 0; d < 16; ++d) e[d] = E[n * 16 + d];
    float v[8];
    float mx = 0.f;
#pragma unroll
    for (int r = 0; r < 8; ++r) {
        int m = r * 256 + tid;
        const float4* Er = (const float4*)(E + (size_t)m * 16);
        float4 a = Er[0], b = Er[1], c = Er[2], d4 = Er[3];
        float s = 0.f;
        s = fmaf(a.x, e[0], s);  s = fmaf(a.y, e[1], s);
        s = fmaf(a.z, e[2], s);  s = fmaf(a.w, e[3], s);
        s = fmaf(b.x, e[4], s);  s = fmaf(b.y, e[5], s);
        s = fmaf(b.z, e[6], s);  s = fmaf(b.w, e[7], s);
        s = fmaf(c.x, e[8], s);  s = fmaf(c.y, e[9], s);
        s = fmaf(c.z, e[10], s); s = fmaf(c.w, e[11], s);
        s = fmaf(d4.x, e[12], s); s = fmaf(d4.y, e[13], s);
        s = fmaf(d4.z, e[14], s); s = fmaf(d4.w, e[15], s);
        s = fmaxf(s, 0.f);                 // relu
        v[r] = s;
        mx = fmaxf(mx, s);
    }
    for (int off = 32; off; off >>= 1) mx = fmaxf(mx, __shfl_down(mx, off, 64));
    if (lane == 0) red[wave] = mx;
    __syncthreads();
    mx = fmaxf(fmaxf(red[0], red[1]), fmaxf(red[2], red[3]));
    __syncthreads();
    float sum = 0.f;
#pragma unroll
    for (int r = 0; r < 8; ++r) { v[r] = __expf(v[r] - mx); sum += v[r]; }
    for (int off = 32; off; off >>= 1) sum += __shfl_down(sum, off, 64);
    if (lane == 0) red[wave] = sum;
    __syncthreads();
    sum = red[0] + red[1] + red[2] + red[3];
    float inv = 1.f / sum;
#pragma unroll
    for (int r = 0; r < 8; ++r)
        Acat[(size_t)n * 4096 + r * 256 + tid] = f2bf(v[r] * inv);
}

// ---------------------------------------------------------------- fused casts (adj + saw)
__global__ __launch_bounds__(256)
void cast_inputs(const float* __restrict__ adj, const float* __restrict__ saw,
                 u16* __restrict__ Acat, u16* __restrict__ sawb) {
    int bid = blockIdx.x;
    if (bid < 4096) {
        size_t j = ((size_t)bid * 256 + threadIdx.x) * 4;
        float4 v = *(const float4*)(adj + j);
        int n = (int)(j >> 11), c = (int)(j & 2047);
        ushort4 o = make_ushort4(f2bf(v.x), f2bf(v.y), f2bf(v.z), f2bf(v.w));
        *(ushort4*)(Acat + (size_t)n * 4096 + 2048 + c) = o;
    } else {
        size_t j = ((size_t)(bid - 4096) * 256 + threadIdx.x) * 4;
        float4 v = *(const float4*)(saw + j);
        ushort4 o = make_ushort4(f2bf(v.x), f2bf(v.y), f2bf(v.z), f2bf(v.w));
        *(ushort4*)(sawb + j) = o;
    }
}

// x[b,m,c] -> XtT[(b*64+c)][m]  (bf16)
__global__ __launch_bounds__(256)
void build_xtT(const float* __restrict__ x, u16* __restrict__ xtT) {
    __shared__ u16 t[64][65];
    int b = blockIdx.y, m0 = blockIdx.x * 64;
    int c = threadIdx.x & 63, g = threadIdx.x >> 6;
#pragma unroll
    for (int r = 0; r < 16; ++r) {
        int mm = g * 16 + r;
        t[mm][c] = f2bf(x[((size_t)b * 2048 + m0 + mm) * 64 + c]);
    }
    __syncthreads();
#pragma unroll
    for (int r = 0; r < 16; ++r) {
        int cc = g * 16 + r;
        xtT[((size_t)b * 64 + cc) * 2048 + m0 + c] = t[c][cc];
    }
}

// ---------------------------------------------------------------- GEMM
// C[m,n] = sum_k A[m,k]*Bt[n,k]. BM=128, BN=64, BK=64, XOR-swizzled LDS.
// Split-K via gridDim.z; fp32 partial -> Cf + z*M*N.
__global__ __launch_bounds__(256, 4)
void gemm_bt(const u16* __restrict__ A, const u16* __restrict__ Bt,
             float* __restrict__ Cf, int M, int N, int K, int Kh) {
    __shared__ alignas(16) u16 As[128 * 64];   // 16 KB
    __shared__ alignas(16) u16 Bs[64 * 64];    //  8 KB
    const int tid = threadIdx.x, lane = tid & 63, wave = tid >> 6;
    const int m0 = blockIdx.y * 128, n0 = blockIdx.x * 64;
    const int wm = (wave >> 1) * 64, wn = (wave & 1) * 32;
    const int kbeg = blockIdx.z * Kh, kend = kbeg + Kh;
    const int ml = lane & 15, c0l = lane >> 4;
    f32x4 acc[4][2] = {};

    int baseA[4], mskA[4], baseB[2], mskB[2];
#pragma unroll
    for (int i = 0; i < 4; ++i) { int m = wm + i * 16 + ml; baseA[i] = m * 8; mskA[i] = m & 7; }
#pragma unroll
    for (int j = 0; j < 2; ++j) { int nn = wn + j * 16 + ml; baseB[j] = nn * 8; mskB[j] = nn & 7; }

    for (int k0 = kbeg; k0 < kend; k0 += 64) {
#pragma unroll
        for (int r = 0; r < 4; ++r) {           // A: 1024 16B-chunks
            int s = wave * 64 + r * 256 + lane;
            int row = s >> 3, gc = (s & 7) ^ (row & 7);
            u16* lds = As + (wave * 64 + r * 256) * 8;   // wave-uniform base
            gl_lds16(A + (size_t)(m0 + row) * K + k0 + gc * 8, lds);
        }
#pragma unroll
        for (int r = 0; r < 2; ++r) {           // B: 512 16B-chunks
            int s = wave * 64 + r * 256 + lane;
            int row = s >> 3, gc = (s & 7) ^ (row & 7);
            u16* lds = Bs + (wave * 64 + r * 256) * 8;
            gl_lds16(Bt + (size_t)(n0 + row) * K + k0 + gc * 8, lds);
        }
        __syncthreads();
#pragma unroll
        for (int ks8 = 0; ks8 < 8; ks8 += 4) {
            bf16x8 af[4], bv[2];
#pragma unroll
            for (int i = 0; i < 4; ++i)
                af[i] = *(const bf16x8*)(As + (baseA[i] + ((c0l + ks8) ^ mskA[i])) * 8);
#pragma unroll
            for (int j = 0; j < 2; ++j)
                bv[j] = *(const bf16x8*)(Bs + (baseB[j] + ((c0l + ks8) ^ mskB[j])) * 8);
#pragma unroll
            for (int i = 0; i < 4; ++i)
#pragma unroll
                for (int j = 0; j < 2; ++j)
                    acc[i][j] = __builtin_amdgcn_mfma_f32_16x16x32_bf16(af[i], bv[j], acc[i][j], 0, 0, 0);
        }
        __syncthreads();
    }

    const int col_l = lane & 15, row_l = (lane >> 4) * 4;
    float* Cfp = Cf + (size_t)blockIdx.z * M * N;
#pragma unroll
    for (int i = 0; i < 4; ++i)
#pragma unroll
        for (int j = 0; j < 2; ++j)
#pragma unroll
            for (int r = 0; r < 4; ++r) {
                int row = m0 + wm + i * 16 + row_l + r;
                int col = n0 + wn + j * 16 + col_l;
                Cfp[(size_t)row * N + col] = acc[i][j][r];
            }
}

// ---------------------------------------------------------------- split-K reduces
// S = sig(z)*adj + (1-sig(z))*sup;  sup read from Acat left half (stride 4096)
__global__ __launch_bounds__(256)
void reduce_z(const float* __restrict__ p, const float* __restrict__ adj,
              const u16* __restrict__ Acat, u16* __restrict__ S) {
    size_t j = ((size_t)blockIdx.x * 256 + threadIdx.x) * 4;
    float4 a = *(const float4*)(p + j);
    float4 b = *(const float4*)(p + (size_t)2048 * 2048 + j);
    float4 ad = *(const float4*)(adj + j);
    int row = (int)(j >> 11), col = (int)(j & 2047);
    ushort4 sp = *(const ushort4*)(Acat + (size_t)row * 4096 + col);
    float z0 = a.x + b.x, z1 = a.y + b.y, z2 = a.z + b.z, z3 = a.w + b.w;
    float s0 = 1.f / (1.f + __expf(-z0)), s1 = 1.f / (1.f + __expf(-z1));
    float s2 = 1.f / (1.f + __expf(-z2)), s3 = 1.f / (1.f + __expf(-z3));
    ushort4 o = make_ushort4(
        f2bf(s0 * ad.x + (1.f - s0) * bf2f(sp.x)),
        f2bf(s1 * ad.y + (1.f - s1) * bf2f(sp.y)),
        f2bf(s2 * ad.z + (1.f - s2) * bf2f(sp.z)),
        f2bf(s3 * ad.w + (1.f - s3) * bf2f(sp.w)));
    *(ushort4*)(S + j) = o;
}

// G1 reduce + transpose: xg1[m][c] = f2bf(p0+p1); xg1T[c][m] = same
__global__ __launch_bounds__(256)
void reduceT(const float* __restrict__ p, u16* __restrict__ xg1,
             u16* __restrict__ xg1T) {
    __shared__ u16 t[64][65];
    int bx = blockIdx.x * 64, by = blockIdx.y * 64;
    int c = threadIdx.x & 63, g = threadIdx.x >> 6;
#pragma unroll
    for (int r = 0; r < 16; ++r) {
        int row = g * 16 + r;
        size_t idx = (size_t)(by + row) * 2048 + bx + c;
        u16 v = f2bf(p[idx] + p[(size_t)2048 * 2048 + idx]);
        xg1[idx] = v;
        t[row][c] = v;
    }
    __syncthreads();
#pragma unroll
    for (int r = 0; r < 16; ++r) {
        int row = g * 16 + r;
        xg1T[(size_t)(bx + row) * 2048 + by + c] = t[c][row];
    }
}

// G2 reduce: xg2raw = f2bf(p0+p1)   ("2*" and "-X" folded into gconv weights)
__global__ __launch_bounds__(256)
void reduce2(const float* __restrict__ p, u16* __restrict__ xg2) {
    size_t j = ((size_t)blockIdx.x * 256 + threadIdx.x) * 4;
    float4 a = *(const float4*)(p + j);
    float4 b = *(const float4*)(p + (size_t)2048 * 2048 + j);
    *(ushort4*)(xg2 + j) = make_ushort4(f2bf(a.x + b.x), f2bf(a.y + b.y),
                                        f2bf(a.z + b.z), f2bf(a.w + b.w));
}

// ---------------------------------------------------------------- wgen: Wn[n][kio] = sum_d E[n,d] Wp[d][kio]
__global__ __launch_bounds__(256)
void wgen(const float* __restrict__ E, const float* __restrict__ Wp,
          u16* __restrict__ Wn) {
    __shared__ float Es[128 * 16];
    const int tid = threadIdx.x;
    const int c0 = blockIdx.x * 512, nb = blockIdx.y * 128;
    const int i4 = (tid & 127) * 4, ng = tid >> 7;
    for (int j = tid; j < 2048; j += 256) Es[j] = E[nb * 16 + j];
    float4 wpv[16];
#pragma unroll
    for (int d = 0; d < 16; ++d)
        wpv[d] = *(const float4*)(Wp + (size_t)d * 12288 + c0 + i4);
    __syncthreads();
    for (int nl = 0; nl < 64; ++nl) {
        int n = ng * 64 + nl;
        float4 s = make_float4(0.f, 0.f, 0.f, 0.f);
#pragma unroll
        for (int d = 0; d < 16; ++d) {
            float e = Es[n * 16 + d];
            s.x = fmaf(e, wpv[d].x, s.x);
            s.y = fmaf(e, wpv[d].y, s.y);
            s.z = fmaf(e, wpv[d].z, s.z);
            s.w = fmaf(e, wpv[d].w, s.w);
        }
        ushort4 o = make_ushort4(f2bf(s.x), f2bf(s.y), f2bf(s.z), f2bf(s.w));
        *(ushort4*)(Wn + (size_t)(nb + n) * 12288 + c0 + i4) = o;
    }
}

// ---------------------------------------------------------------- final gconv (bf16 LDS, 38 KB -> 4 blocks/CU)
__global__ __launch_bounds__(256, 4)
void gconv(const float* __restrict__ x, const float* __restrict__ E,
           const u16* __restrict__ Wn, const float* __restrict__ bp,
           const u16* __restrict__ xg1, const u16* __restrict__ xg2,
           float* __restrict__ out) {
    const int n = blockIdx.x, tid = threadIdx.x;
    __shared__ alignas(16) u16 wl[3 * 64 * 64];   // 24 KB bf16
    __shared__ alignas(16) u16 xl[3 * 32 * 72];   // 13.5 KB bf16, stride 72
    __shared__ float bl[64];
    // load raw weights (perfectly coalesced 16B/lane)
    const u16* wrow = Wn + (size_t)n * 12288;
    for (int j = tid * 8; j < 12288; j += 2048)
        *(u16x8*)(wl + j) = *(const u16x8*)(wrow + j);
    if (tid < 64) {
        float s = 0.f;
#pragma unroll
        for (int d = 0; d < 16; ++d) s = fmaf(E[n * 16 + d], bp[d * 64 + tid], s);
        bl[tid] = s;
    }
    // stage x_g rows (bf16): k=0 from x (cast), k=1/2 from xg1/xg2raw
    {
        const int b = tid >> 3, i = (tid & 7) * 8;
        *(u16x8*)(xl + 2304 + b * 72 + i) = *(const u16x8*)(xg1 + (size_t)n * 2048 + tid * 8);
        *(u16x8*)(xl + 4608 + b * 72 + i) = *(const u16x8*)(xg2 + (size_t)n * 2048 + tid * 8);
        float4 xa = *(const float4*)(x + ((size_t)b * 2048 + n) * 64 + i);
        float4 xb = *(const float4*)(x + ((size_t)b * 2048 + n) * 64 + i + 4);
        u16x8 xc;
        xc[0] = f2bf(xa.x); xc[1] = f2bf(xa.y); xc[2] = f2bf(xa.z); xc[3] = f2bf(xa.w);
        xc[4] = f2bf(xb.x); xc[5] = f2bf(xb.y); xc[6] = f2bf(xb.z); xc[7] = f2bf(xb.w);
        *(u16x8*)(xl + b * 72 + i) = xc;
    }
    __syncthreads();
    // weight transform in LDS: W0' = W0 - W2, W2' = 2*W2   (xg2 is raw S@xg1)
    for (int j = tid * 8; j < 4096; j += 2048) {
        u16x8 w0 = *(const u16x8*)(wl + j);
        u16x8 w2 = *(const u16x8*)(wl + 8192 + j);
        u16x8 o0, o2;
#pragma unroll
        for (int t = 0; t < 8; ++t) {
            float f2 = bf2f(w2[t]);
            o0[t] = f2bf(bf2f(w0[t]) - f2);
            o2[t] = f2bf(2.f * f2);
        }
        *(u16x8*)(wl + j) = o0;
        *(u16x8*)(wl + 8192 + j) = o2;
    }
    __syncthreads();
    const int b = tid >> 3, og = tid & 7;
    float acc[8];
#pragma unroll
    for (int t = 0; t < 8; ++t) acc[t] = bl[og * 8 + t];
#pragma unroll
    for (int k = 0; k < 3; ++k) {
        const u16* xr = xl + k * 2304 + b * 72;
        const u16* wr = wl + k * 4096 + og * 8;
#pragma unroll 4
        for (int i = 0; i < 64; ++i) {
            float xv = bf2f(xr[i]);
            u16x8 w = *(const u16x8*)(wr + i * 64);
            acc[0] = fmaf(bf2f(w[0]), xv, acc[0]);
            acc[1] = fmaf(bf2f(w[1]), xv, acc[1]);
            acc[2] = fmaf(bf2f(w[2]), xv, acc[2]);
            acc[3] = fmaf(bf2f(w[3]), xv, acc[3]);
            acc[4] = fmaf(bf2f(w[4]), xv, acc[4]);
            acc[5] = fmaf(bf2f(w[5]), xv, acc[5]);
            acc[6] = fmaf(bf2f(w[6]), xv, acc[6]);
            acc[7] = fmaf(bf2f(w[7]), xv, acc[7]);
        }
    }
    float* op = out + ((size_t)b * 2048 + n) * 64 + og * 8;
    *(float4*)op       = make_float4(acc[0], acc[1], acc[2], acc[3]);
    *((float4*)op + 1) = make_float4(acc[4], acc[5], acc[6], acc[7]);
}

// ---------------------------------------------------------------- launch
extern "C" void kernel_launch(void* const* d_in, const int* in_sizes, int n_in,
                              void* d_out, int out_size, void* d_ws, size_t ws_size,
                              hipStream_t stream) {
    const float* x   = (const float*)d_in[0];   // [32,2048,64]
    const float* E   = (const float*)d_in[1];   // [2048,16]
    const float* adj = (const float*)d_in[2];   // [2048,2048]
    const float* Wp  = (const float*)d_in[3];   // [16,3,64,64]
    const float* bp  = (const float*)d_in[4];   // [16,64]
    const float* saw = (const float*)d_in[5];   // [2048,4096]
    float* out = (float*)d_out;

    char* ws = (char*)d_ws;
    const size_t MB = 1u << 20;
    u16*   Acat  = (u16*)(ws);                  // [0,16M)
    u16*   sawb  = (u16*)(ws + 16 * MB);        // [16,32M)
    u16*   XtT   = (u16*)(ws + 32 * MB);        // [32,40M)
    float* part  = (float*)(ws + 48 * MB);      // [48,80M) split-K fp32 partials
    u16*   S_bf  = (u16*)(ws + 16 * MB);        // [16,24M) after sawb dead
    u16*   xg1T  = (u16*)(ws + 24 * MB);        // [24,32M)
    u16*   xg1_bf= (u16*)(ws);                  // [0,8M)   after Acat dead
    u16*   xg2_bf= (u16*)(ws + 8 * MB);         // [8,16M)
    u16*   Wn    = (u16*)(ws + 24 * MB);        // [24,72M) after G2 read xg1T

    supports_softmax<<<2048, 256, 0, stream>>>(E, Acat);
    cast_inputs<<<12288, 256, 0, stream>>>(adj, saw, Acat, sawb);
    build_xtT<<<dim3(32, 32), 256, 0, stream>>>(x, XtT);

    // z = Acat @ sawb^T (split-K=2)
    gemm_bt<<<dim3(32, 16, 2), 256, 0, stream>>>(Acat, sawb, part, 2048, 2048, 4096, 2048);
    reduce_z<<<4096, 256, 0, stream>>>(part, adj, Acat, S_bf);
    // G1: xg1 = S @ X  (Bt = XtT), split-K=2
    gemm_bt<<<dim3(32, 16, 2), 256, 0, stream>>>(S_bf, XtT, part, 2048, 2048, 2048, 1024);
    reduceT<<<dim3(32, 32), 256, 0, stream>>>(part, xg1_bf, xg1T);
    // G2: xg2raw = S @ xg1  (Bt = xg1T), split-K=2
    gemm_bt<<<dim3(32, 16, 2), 256, 0, stream>>>(S_bf, xg1T, part, 2048, 2048, 2048, 1024);
    reduce2<<<4096, 256, 0, stream>>>(part, xg2_bf);

    wgen<<<dim3(24, 16), 256, 0, stream>>>(E, Wp, Wn);
    gconv<<<2048, 256, 0, stream>>>(x, E, Wn, bp, xg1_bf, xg2_bf, out);
}

// Round 5
// 306.237 us; speedup vs baseline: 1.5525x; 1.0809x over previous
//
#include <hip/hip_runtime.h>

// AVWGCN: B=32, N=2048, C=64, O=64, K=3, D=16
// R5 changes vs R4:
//  - gconv rewritten as MFMA (was VALU-bound at 54us, VALUBusy 66%): per 128-row tile of
//    (b,n), loop d=0..15: stage Wp'_d [192x64] bf16 in LDS, 48 MFMA/wave, scale-add into
//    out-acc with E[n,d] per row. A-fragments (XG tile, d-invariant) preloaded into regs
//    (96 VGPR) -> per-d LDS = B-reads only. wgen + Wn (48MB x2 traffic) eliminated.
//  - prep kernel: Wp'_bt[d][o][ki] bf16 with W0'=W0-W2, W2'=2W2 folded; bias[n][o]=E@bp.
//  - reduceT/reduce2 write xg in [b,n,c] layout (gconv A operand); x_bf cast added.
//  - GEMMs: 128x128 tile (LDS:MFMA balanced 8 reads:16 MFMA vs 6:8 at BN=64), BK=64
//    XOR-swizzle, split-K=4 with bf16 partials (32 MB), grid 1024 blocks.
// Workspace (80 MiB):
//  [0,16M) Acat -> xg1_bnc [0,8M) + xg2_bnc [8,16M)
//  [16,32M) sawb -> S_bf [16,24M) + xg1T [24,32M)
//  [32,40M) XtT -> (after G1) Wpb [32,32.4M) + bias [33,33.5M)
//  [40,48M) x_bf   [48,80M) 4x bf16 split-K partials (z, G1, G2 sequential)

typedef unsigned short u16;
typedef float f32x4 __attribute__((ext_vector_type(4)));
typedef __bf16 bf16x8 __attribute__((ext_vector_type(8)));
typedef unsigned short u16x8 __attribute__((ext_vector_type(8)));

__device__ __forceinline__ u16 f2bf(float f) {
    unsigned u = __float_as_uint(f);
    u += 0x7FFFu + ((u >> 16) & 1u);   // RNE
    return (u16)(u >> 16);
}
__device__ __forceinline__ float bf2f(u16 h) {
    return __uint_as_float((unsigned)h << 16);
}
__device__ __forceinline__ void gl_lds16(const void* g, void* l) {
    __builtin_amdgcn_global_load_lds(
        (const __attribute__((address_space(1))) unsigned*)g,
        (__attribute__((address_space(3))) unsigned*)l, 16, 0, 0);
}

// ---------------------------------------------------------------- supports
__global__ __launch_bounds__(256)
void supports_softmax(const float* __restrict__ E, u16* __restrict__ Acat) {
    const int n = blockIdx.x, tid = threadIdx.x;
    const int lane = tid & 63, wave = tid >> 6;
    __shared__ float red[4];
    float e[16];
#pragma unroll
    for (int d = 0; d < 16; ++d) e[d] = E[n * 16 + d];
    float v[8];
    float mx = 0.f;
#pragma unroll
    for (int r = 0; r < 8; ++r) {
        int m = r * 256 + tid;
        const float4* Er = (const float4*)(E + (size_t)m * 16);
        float4 a = Er[0], b = Er[1], c = Er[2], d4 = Er[3];
        float s = 0.f;
        s = fmaf(a.x, e[0], s);  s = fmaf(a.y, e[1], s);
        s = fmaf(a.z, e[2], s);  s = fmaf(a.w, e[3], s);
        s = fmaf(b.x, e[4], s);  s = fmaf(b.y, e[5], s);
        s = fmaf(b.z, e[6], s);  s = fmaf(b.w, e[7], s);
        s = fmaf(c.x, e[8], s);  s = fmaf(c.y, e[9], s);
        s = fmaf(c.z, e[10], s); s = fmaf(c.w, e[11], s);
        s = fmaf(d4.x, e[12], s); s = fmaf(d4.y, e[13], s);
        s = fmaf(d4.z, e[14], s); s = fmaf(d4.w, e[15], s);
        s = fmaxf(s, 0.f);                 // relu
        v[r] = s;
        mx = fmaxf(mx, s);
    }
    for (int off = 32; off; off >>= 1) mx = fmaxf(mx, __shfl_down(mx, off, 64));
    if (lane == 0) red[wave] = mx;
    __syncthreads();
    mx = fmaxf(fmaxf(red[0], red[1]), fmaxf(red[2], red[3]));
    __syncthreads();
    float sum = 0.f;
#pragma unroll
    for (int r = 0; r < 8; ++r) { v[r] = __expf(v[r] - mx); sum += v[r]; }
    for (int off = 32; off; off >>= 1) sum += __shfl_down(sum, off, 64);
    if (lane == 0) red[wave] = sum;
    __syncthreads();
    sum = red[0] + red[1] + red[2] + red[3];
    float inv = 1.f / sum;
#pragma unroll
    for (int r = 0; r < 8; ++r)
        Acat[(size_t)n * 4096 + r * 256 + tid] = f2bf(v[r] * inv);
}

// ---------------------------------------------------------------- fused casts (adj + saw + x)
__global__ __launch_bounds__(256)
void cast_inputs(const float* __restrict__ adj, const float* __restrict__ saw,
                 const float* __restrict__ x, u16* __restrict__ Acat,
                 u16* __restrict__ sawb, u16* __restrict__ x_bf) {
    int bid = blockIdx.x;
    if (bid < 4096) {
        size_t j = ((size_t)bid * 256 + threadIdx.x) * 4;
        float4 v = *(const float4*)(adj + j);
        int n = (int)(j >> 11), c = (int)(j & 2047);
        ushort4 o = make_ushort4(f2bf(v.x), f2bf(v.y), f2bf(v.z), f2bf(v.w));
        *(ushort4*)(Acat + (size_t)n * 4096 + 2048 + c) = o;
    } else if (bid < 12288) {
        size_t j = ((size_t)(bid - 4096) * 256 + threadIdx.x) * 4;
        float4 v = *(const float4*)(saw + j);
        ushort4 o = make_ushort4(f2bf(v.x), f2bf(v.y), f2bf(v.z), f2bf(v.w));
        *(ushort4*)(sawb + j) = o;
    } else {
        size_t j = ((size_t)(bid - 12288) * 256 + threadIdx.x) * 4;
        float4 v = *(const float4*)(x + j);
        ushort4 o = make_ushort4(f2bf(v.x), f2bf(v.y), f2bf(v.z), f2bf(v.w));
        *(ushort4*)(x_bf + j) = o;
    }
}

// x[b,m,c] -> XtT[(b*64+c)][m]  (bf16)
__global__ __launch_bounds__(256)
void build_xtT(const float* __restrict__ x, u16* __restrict__ xtT) {
    __shared__ u16 t[64][65];
    int b = blockIdx.y, m0 = blockIdx.x * 64;
    int c = threadIdx.x & 63, g = threadIdx.x >> 6;
#pragma unroll
    for (int r = 0; r < 16; ++r) {
        int mm = g * 16 + r;
        t[mm][c] = f2bf(x[((size_t)b * 2048 + m0 + mm) * 64 + c]);
    }
    __syncthreads();
#pragma unroll
    for (int r = 0; r < 16; ++r) {
        int cc = g * 16 + r;
        xtT[((size_t)b * 64 + cc) * 2048 + m0 + c] = t[c][cc];
    }
}

// ---------------------------------------------------------------- GEMM 128x128, BK=64, split-K
// C[m,n] = sum_k A[m,k]*Bt[n,k]; bf16 partial -> Cp + z*M*N.
__global__ __launch_bounds__(256, 3)
void gemm_bt(const u16* __restrict__ A, const u16* __restrict__ Bt,
             u16* __restrict__ Cp, int M, int N, int K, int Kh) {
    __shared__ alignas(16) u16 As[128 * 64];   // 16 KB
    __shared__ alignas(16) u16 Bs[128 * 64];   // 16 KB
    const int tid = threadIdx.x, lane = tid & 63, wave = tid >> 6;
    const int m0 = blockIdx.y * 128, n0 = blockIdx.x * 128;
    const int wm = (wave >> 1) * 64, wn = (wave & 1) * 64;
    const int kbeg = blockIdx.z * Kh, kend = kbeg + Kh;
    const int ml = lane & 15, c0l = lane >> 4;
    f32x4 acc[4][4] = {};

    int baseA[4], mskA[4], baseB[4], mskB[4];
#pragma unroll
    for (int i = 0; i < 4; ++i) { int m = wm + i * 16 + ml; baseA[i] = m * 8; mskA[i] = m & 7; }
#pragma unroll
    for (int j = 0; j < 4; ++j) { int nn = wn + j * 16 + ml; baseB[j] = nn * 8; mskB[j] = nn & 7; }

    for (int k0 = kbeg; k0 < kend; k0 += 64) {
#pragma unroll
        for (int r = 0; r < 4; ++r) {           // A: 1024 16B-chunks
            int s = wave * 64 + r * 256 + lane;
            int row = s >> 3, gc = (s & 7) ^ (row & 7);
            gl_lds16(A + (size_t)(m0 + row) * K + k0 + gc * 8, As + (size_t)s * 8);
        }
#pragma unroll
        for (int r = 0; r < 4; ++r) {           // B: 1024 16B-chunks
            int s = wave * 64 + r * 256 + lane;
            int row = s >> 3, gc = (s & 7) ^ (row & 7);
            gl_lds16(Bt + (size_t)(n0 + row) * K + k0 + gc * 8, Bs + (size_t)s * 8);
        }
        __syncthreads();
#pragma unroll
        for (int ks4 = 0; ks4 < 8; ks4 += 4) {
            bf16x8 af[4], bv[4];
#pragma unroll
            for (int i = 0; i < 4; ++i)
                af[i] = *(const bf16x8*)(As + (baseA[i] + ((c0l + ks4) ^ mskA[i])) * 8);
#pragma unroll
            for (int j = 0; j < 4; ++j)
                bv[j] = *(const bf16x8*)(Bs + (baseB[j] + ((c0l + ks4) ^ mskB[j])) * 8);
#pragma unroll
            for (int i = 0; i < 4; ++i)
#pragma unroll
                for (int j = 0; j < 4; ++j)
                    acc[i][j] = __builtin_amdgcn_mfma_f32_16x16x32_bf16(af[i], bv[j], acc[i][j], 0, 0, 0);
        }
        __syncthreads();
    }

    const int col_l = lane & 15, row_l = (lane >> 4) * 4;
    u16* Cz = Cp + (size_t)blockIdx.z * M * N;
#pragma unroll
    for (int i = 0; i < 4; ++i)
#pragma unroll
        for (int j = 0; j < 4; ++j)
#pragma unroll
            for (int r = 0; r < 4; ++r) {
                int row = m0 + wm + i * 16 + row_l + r;
                int col = n0 + wn + j * 16 + col_l;
                Cz[(size_t)row * N + col] = f2bf(acc[i][j][r]);
            }
}

// ---------------------------------------------------------------- split-K reduces
#define PSTRIDE ((size_t)2048 * 2048)
// S = sig(z)*adj + (1-sig(z))*sup;  sup from Acat left half
__global__ __launch_bounds__(256)
void reduce_z(const u16* __restrict__ p, const float* __restrict__ adj,
              const u16* __restrict__ Acat, u16* __restrict__ S) {
    size_t j = ((size_t)blockIdx.x * 256 + threadIdx.x) * 4;
    ushort4 p0 = *(const ushort4*)(p + j);
    ushort4 p1 = *(const ushort4*)(p + PSTRIDE + j);
    ushort4 p2 = *(const ushort4*)(p + 2 * PSTRIDE + j);
    ushort4 p3 = *(const ushort4*)(p + 3 * PSTRIDE + j);
    float4 ad = *(const float4*)(adj + j);
    int row = (int)(j >> 11), col = (int)(j & 2047);
    ushort4 sp = *(const ushort4*)(Acat + (size_t)row * 4096 + col);
    float z0 = bf2f(p0.x) + bf2f(p1.x) + bf2f(p2.x) + bf2f(p3.x);
    float z1 = bf2f(p0.y) + bf2f(p1.y) + bf2f(p2.y) + bf2f(p3.y);
    float z2 = bf2f(p0.z) + bf2f(p1.z) + bf2f(p2.z) + bf2f(p3.z);
    float z3 = bf2f(p0.w) + bf2f(p1.w) + bf2f(p2.w) + bf2f(p3.w);
    float s0 = 1.f / (1.f + __expf(-z0)), s1 = 1.f / (1.f + __expf(-z1));
    float s2 = 1.f / (1.f + __expf(-z2)), s3 = 1.f / (1.f + __expf(-z3));
    ushort4 o = make_ushort4(
        f2bf(s0 * ad.x + (1.f - s0) * bf2f(sp.x)),
        f2bf(s1 * ad.y + (1.f - s1) * bf2f(sp.y)),
        f2bf(s2 * ad.z + (1.f - s2) * bf2f(sp.z)),
        f2bf(s3 * ad.w + (1.f - s3) * bf2f(sp.w)));
    *(ushort4*)(S + j) = o;
}

// G1 reduce: xg1_bnc[b,n,c] (gconv A layout) + xg1T[(b,c)][n] (G2 Bt operand)
__global__ __launch_bounds__(256)
void reduceT(const u16* __restrict__ p, u16* __restrict__ xg1b,
             u16* __restrict__ xg1T) {
    __shared__ u16 t[64][65];
    int bx = blockIdx.x * 64, by = blockIdx.y * 64;   // bx: (b,c) cols, by: n rows
    int c = threadIdx.x & 63, g = threadIdx.x >> 6;
    int b = bx >> 6;
#pragma unroll
    for (int r = 0; r < 16; ++r) {
        int row = g * 16 + r;                          // n - by
        size_t idx = (size_t)(by + row) * 2048 + bx + c;
        u16 v = f2bf(bf2f(p[idx]) + bf2f(p[PSTRIDE + idx]) +
                     bf2f(p[2 * PSTRIDE + idx]) + bf2f(p[3 * PSTRIDE + idx]));
        xg1b[((size_t)b * 2048 + by + row) * 64 + c] = v;
        t[row][c] = v;
    }
    __syncthreads();
#pragma unroll
    for (int r = 0; r < 16; ++r) {
        int row = g * 16 + r;
        xg1T[(size_t)(bx + row) * 2048 + by + c] = t[c][row];
    }
}

// G2 reduce -> xg2_bnc[b,n,c]  (raw S@xg1; 2x / -x folded into weights)
__global__ __launch_bounds__(256)
void reduce2(const u16* __restrict__ p, u16* __restrict__ xg2b) {
    size_t j = ((size_t)blockIdx.x * 256 + threadIdx.x) * 4;
    ushort4 p0 = *(const ushort4*)(p + j);
    ushort4 p1 = *(const ushort4*)(p + PSTRIDE + j);
    ushort4 p2 = *(const ushort4*)(p + 2 * PSTRIDE + j);
    ushort4 p3 = *(const ushort4*)(p + 3 * PSTRIDE + j);
    int n = (int)(j >> 11), bc = (int)(j & 2047);
    int b = bc >> 6, c = bc & 63;
    ushort4 o = make_ushort4(
        f2bf(bf2f(p0.x) + bf2f(p1.x) + bf2f(p2.x) + bf2f(p3.x)),
        f2bf(bf2f(p0.y) + bf2f(p1.y) + bf2f(p2.y) + bf2f(p3.y)),
        f2bf(bf2f(p0.z) + bf2f(p1.z) + bf2f(p2.z) + bf2f(p3.z)),
        f2bf(bf2f(p0.w) + bf2f(p1.w) + bf2f(p2.w) + bf2f(p3.w)));
    *(ushort4*)(xg2b + ((size_t)b * 2048 + n) * 64 + c) = o;
}

// ---------------------------------------------------------------- prep: Wp'_bt + bias table
// Wpb[d][o][ki] bf16, ki = k*64+i, with W0' = W0 - W2, W2' = 2*W2. bias[n][o] = E@bp.
__global__ __launch_bounds__(256)
void prep(const float* __restrict__ Wp, const float* __restrict__ E,
          const float* __restrict__ bp, u16* __restrict__ Wpb,
          float* __restrict__ bias) {
    const int bid = blockIdx.x, tid = threadIdx.x;
    if (bid < 16) {
        const int d = bid;
        const float* base = Wp + (size_t)d * 12288;    // [k][i][o]
        for (int idx = tid; idx < 12288; idx += 256) {
            int o = idx / 192, ki = idx - o * 192;
            int k = ki >> 6, i = ki & 63;
            float v;
            if (k == 0)      v = base[i * 64 + o] - base[2 * 4096 + i * 64 + o];
            else if (k == 1) v = base[4096 + i * 64 + o];
            else             v = 2.f * base[2 * 4096 + i * 64 + o];
            Wpb[(size_t)(d * 64 + o) * 192 + ki] = f2bf(v);
        }
    } else {
        const int nb = bid - 16;                       // 64 blocks x 32 n
#pragma unroll
        for (int it = 0; it < 8; ++it) {
            int idx = tid + it * 256;
            int n = nb * 32 + (idx >> 6), o = idx & 63;
            float s = 0.f;
#pragma unroll
            for (int d = 0; d < 16; ++d) s = fmaf(E[n * 16 + d], bp[d * 64 + o], s);
            bias[(size_t)n * 64 + o] = s;
        }
    }
}

// ---------------------------------------------------------------- gconv MFMA
// out[row=(b,n), o] = bias[n,o] + sum_d E[n,d] * (XG[row,:] @ Wp'_d)   K=192
// XG row = [x_bf | xg1 | xg2][row][0:64 each]. A-frags preloaded (d-invariant).
__global__ __launch_bounds__(256, 2)
void gconv_mfma(const u16* __restrict__ x_bf, const u16* __restrict__ xg1,
                const u16* __restrict__ xg2, const u16* __restrict__ Wpb,
                const float* __restrict__ bias, const float* __restrict__ E,
                float* __restrict__ out) {
    __shared__ alignas(16) u16 As[128 * 192];   // 48 KB, XOR-swizzled chunks
    __shared__ alignas(16) u16 Bs[64 * 192];    // 24 KB
    __shared__ float El[16 * 128];              //  8 KB, [d][row]
    const int tid = threadIdx.x, lane = tid & 63, wave = tid >> 6;
    const int m0 = blockIdx.x * 128, nb = m0 & 2047;
    const int wm = (wave >> 1) * 64, wn = (wave & 1) * 32;
    const int ml = lane & 15, c0l = lane >> 4;
    const int col_l = lane & 15, rl = (lane >> 4) * 4;

    // stage A: 128 rows x 24 chunks; slot sc holds global chunk (sc&24)|((sc^row)&7)
#pragma unroll
    for (int it = 0; it < 12; ++it) {
        int s = tid + it * 256;
        int row = s / 24, sc = s - row * 24;
        int gc = (sc & 24) | ((sc ^ row) & 7);
        const u16* src = (gc < 8) ? x_bf : (gc < 16 ? xg1 : xg2);
        gl_lds16(src + (size_t)(m0 + row) * 64 + (gc & 7) * 8, As + (size_t)s * 8);
    }
    // stage El transposed [d][128]
#pragma unroll
    for (int it = 0; it < 8; ++it) {
        int idx = tid + it * 256;
        El[idx] = E[(size_t)(nb + (idx & 127)) * 16 + (idx >> 7)];
    }
    // init out-acc from bias
    f32x4 oacc[4][2];
#pragma unroll
    for (int i = 0; i < 4; ++i)
#pragma unroll
        for (int j = 0; j < 2; ++j)
#pragma unroll
            for (int r = 0; r < 4; ++r)
                oacc[i][j][r] = bias[(size_t)(nb + wm + i * 16 + rl + r) * 64 + wn + j * 16 + col_l];
    __syncthreads();

    // preload A fragments (d-invariant): af[i][ks]
    bf16x8 af[4][6];
#pragma unroll
    for (int i = 0; i < 4; ++i) {
        int m = wm + i * 16 + ml, base = m * 24, msk = m & 7;
#pragma unroll
        for (int ks = 0; ks < 6; ++ks) {
            int c = c0l + ks * 4;
            af[i][ks] = *(const bf16x8*)(As + (base + ((c & 24) | ((c ^ msk) & 7))) * 8);
        }
    }

    for (int d = 0; d < 16; ++d) {
        if (d) __syncthreads();                 // protect Bs from overwrite
#pragma unroll
        for (int it = 0; it < 6; ++it) {        // stage Wp'_d: 64 rows x 24 chunks
            int s = tid + it * 256;
            int row = s / 24, sc = s - row * 24;
            int gc = (sc & 24) | ((sc ^ row) & 7);
            gl_lds16(Wpb + (size_t)(d * 64 + row) * 192 + gc * 8, Bs + (size_t)s * 8);
        }
        __syncthreads();
        f32x4 tmp[4][2] = {};
#pragma unroll
        for (int ks = 0; ks < 6; ++ks) {
            bf16x8 bv[2];
#pragma unroll
            for (int j = 0; j < 2; ++j) {
                int o = wn + j * 16 + ml, msk = o & 7, c = c0l + ks * 4;
                bv[j] = *(const bf16x8*)(Bs + (o * 24 + ((c & 24) | ((c ^ msk) & 7))) * 8);
            }
#pragma unroll
            for (int i = 0; i < 4; ++i)
#pragma unroll
                for (int j = 0; j < 2; ++j)
                    tmp[i][j] = __builtin_amdgcn_mfma_f32_16x16x32_bf16(af[i][ks], bv[j], tmp[i][j], 0, 0, 0);
        }
        // scale-add: oacc += E[row,d] * tmp
#pragma unroll
        for (int i = 0; i < 4; ++i)
#pragma unroll
            for (int r = 0; r < 4; ++r) {
                float ev = El[d * 128 + wm + i * 16 + rl + r];
#pragma unroll
                for (int j = 0; j < 2; ++j)
                    oacc[i][j][r] = fmaf(ev, tmp[i][j][r], oacc[i][j][r]);
            }
    }
#pragma unroll
    for (int i = 0; i < 4; ++i)
#pragma unroll
        for (int j = 0; j < 2; ++j)
#pragma unroll
            for (int r = 0; r < 4; ++r)
                out[(size_t)(m0 + wm + i * 16 + rl + r) * 64 + wn + j * 16 + col_l] = oacc[i][j][r];
}

// ---------------------------------------------------------------- launch
extern "C" void kernel_launch(void* const* d_in, const int* in_sizes, int n_in,
                              void* d_out, int out_size, void* d_ws, size_t ws_size,
                              hipStream_t stream) {
    const float* x   = (const float*)d_in[0];   // [32,2048,64]
    const float* E   = (const float*)d_in[1];   // [2048,16]
    const float* adj = (const float*)d_in[2];   // [2048,2048]
    const float* Wp  = (const float*)d_in[3];   // [16,3,64,64]
    const float* bp  = (const float*)d_in[4];   // [16,64]
    const float* saw = (const float*)d_in[5];   // [2048,4096]
    float* out = (float*)d_out;

    char* ws = (char*)d_ws;
    const size_t MB = 1u << 20;
    u16*   Acat  = (u16*)(ws);                  // [0,16M)
    u16*   sawb  = (u16*)(ws + 16 * MB);        // [16,32M)
    u16*   XtT   = (u16*)(ws + 32 * MB);        // [32,40M)
    u16*   x_bf  = (u16*)(ws + 40 * MB);        // [40,48M)
    u16*   part  = (u16*)(ws + 48 * MB);        // [48,80M) 4 x 8MB bf16 partials
    u16*   S_bf  = (u16*)(ws + 16 * MB);        // [16,24M) after sawb dead
    u16*   xg1T  = (u16*)(ws + 24 * MB);        // [24,32M)
    u16*   xg1b  = (u16*)(ws);                  // [0,8M)   after Acat dead
    u16*   xg2b  = (u16*)(ws + 8 * MB);         // [8,16M)
    u16*   Wpb   = (u16*)(ws + 32 * MB);        // [32,32.4M) after XtT dead (post-G1)
    float* bias  = (float*)(ws + 33 * MB);      // [33,33.5M)

    supports_softmax<<<2048, 256, 0, stream>>>(E, Acat);
    cast_inputs<<<16384, 256, 0, stream>>>(adj, saw, x, Acat, sawb, x_bf);
    build_xtT<<<dim3(32, 32), 256, 0, stream>>>(x, XtT);

    // z = Acat @ sawb^T, split-K=4
    gemm_bt<<<dim3(16, 16, 4), 256, 0, stream>>>(Acat, sawb, part, 2048, 2048, 4096, 1024);
    reduce_z<<<4096, 256, 0, stream>>>(part, adj, Acat, S_bf);
    // G1: xg1 = S @ X, split-K=4
    gemm_bt<<<dim3(16, 16, 4), 256, 0, stream>>>(S_bf, XtT, part, 2048, 2048, 2048, 512);
    reduceT<<<dim3(32, 32), 256, 0, stream>>>(part, xg1b, xg1T);
    prep<<<80, 256, 0, stream>>>(Wp, E, bp, Wpb, bias);
    // G2: xg2raw = S @ xg1, split-K=4
    gemm_bt<<<dim3(16, 16, 4), 256, 0, stream>>>(S_bf, xg1T, part, 2048, 2048, 2048, 512);
    reduce2<<<4096, 256, 0, stream>>>(part, xg2b);

    gconv_mfma<<<512, 256, 0, stream>>>(x_bf, xg1b, xg2b, Wpb, bias, E, out);
}

// Round 7
// 288.140 us; speedup vs baseline: 1.6500x; 1.0628x over previous
//
#include <hip/hip_runtime.h>

// AVWGCN: B=32, N=2048, C=64, O=64, K=3, D=16
// R7 = R6 fixed:
//  - gconv A-staging: NO global_load_lds under divergence (R6's NaN bug — ragged exec
//    mask breaks the wave-uniform-base+lane*16B LDS dest semantics). All three A-chunk
//    sources (x cast, xg1, G2-partial 4-sum) now use plain loads + explicit LDS stores.
//    B-staging keeps gl_lds16 (full-wave, lane-linear — R5-verified).
//  - Wpb/bias moved from [80,81.5M) (possible ws overrun) into the free [40,48M) hole.
// Structure from R6: fused preamble (supports+casts+xtT+prep), reduce2 folded into
// gconv, x_bf eliminated, reduce_z reads adj bf16 from Acat. 7 dispatches.
// Workspace (80 MiB):
//  [0,16M) Acat -> xg1b [0,8M)        [16,32M) sawb -> S_bf [16,24M) + xg1T [24,32M)
//  [32,40M) XtT   [40,40.4M) Wpb  [41,41.5M) bias   [48,80M) 4x bf16 split-K partials

typedef unsigned short u16;
typedef float f32x4 __attribute__((ext_vector_type(4)));
typedef __bf16 bf16x8 __attribute__((ext_vector_type(8)));
typedef unsigned short u16x8 __attribute__((ext_vector_type(8)));

#define PSTRIDE ((size_t)2048 * 2048)

__device__ __forceinline__ u16 f2bf(float f) {
    unsigned u = __float_as_uint(f);
    u += 0x7FFFu + ((u >> 16) & 1u);   // RNE
    return (u16)(u >> 16);
}
__device__ __forceinline__ float bf2f(u16 h) {
    return __uint_as_float((unsigned)h << 16);
}
__device__ __forceinline__ void gl_lds16(const void* g, void* l) {
    __builtin_amdgcn_global_load_lds(
        (const __attribute__((address_space(1))) unsigned*)g,
        (__attribute__((address_space(3))) unsigned*)l, 16, 0, 0);
}

// ---------------------------------------------------------------- preamble (fused)
// blocks [0,2048): supports softmax row n -> Acat left half
// blocks [2048,6144): adj cast -> Acat right half
// blocks [6144,14336): saw cast -> sawb
// blocks [14336,15360): x -> XtT[(b*64+c)][m] bf16
// blocks [15360,15440): prep Wpb + bias
__global__ __launch_bounds__(256)
void preamble(const float* __restrict__ E, const float* __restrict__ adj,
              const float* __restrict__ saw, const float* __restrict__ x,
              const float* __restrict__ Wp, const float* __restrict__ bp,
              u16* __restrict__ Acat, u16* __restrict__ sawb,
              u16* __restrict__ xtT, u16* __restrict__ Wpb,
              float* __restrict__ bias) {
    __shared__ float red[4];
    __shared__ u16 t[64][65];
    const int bid = blockIdx.x, tid = threadIdx.x;

    if (bid < 2048) {
        const int n = bid, lane = tid & 63, wave = tid >> 6;
        float e[16];
#pragma unroll
        for (int d = 0; d < 16; ++d) e[d] = E[n * 16 + d];
        float v[8];
        float mx = 0.f;
#pragma unroll
        for (int r = 0; r < 8; ++r) {
            int m = r * 256 + tid;
            const float4* Er = (const float4*)(E + (size_t)m * 16);
            float4 a = Er[0], b = Er[1], c = Er[2], d4 = Er[3];
            float s = 0.f;
            s = fmaf(a.x, e[0], s);  s = fmaf(a.y, e[1], s);
            s = fmaf(a.z, e[2], s);  s = fmaf(a.w, e[3], s);
            s = fmaf(b.x, e[4], s);  s = fmaf(b.y, e[5], s);
            s = fmaf(b.z, e[6], s);  s = fmaf(b.w, e[7], s);
            s = fmaf(c.x, e[8], s);  s = fmaf(c.y, e[9], s);
            s = fmaf(c.z, e[10], s); s = fmaf(c.w, e[11], s);
            s = fmaf(d4.x, e[12], s); s = fmaf(d4.y, e[13], s);
            s = fmaf(d4.z, e[14], s); s = fmaf(d4.w, e[15], s);
            s = fmaxf(s, 0.f);
            v[r] = s;
            mx = fmaxf(mx, s);
        }
        for (int off = 32; off; off >>= 1) mx = fmaxf(mx, __shfl_down(mx, off, 64));
        if (lane == 0) red[wave] = mx;
        __syncthreads();
        mx = fmaxf(fmaxf(red[0], red[1]), fmaxf(red[2], red[3]));
        __syncthreads();
        float sum = 0.f;
#pragma unroll
        for (int r = 0; r < 8; ++r) { v[r] = __expf(v[r] - mx); sum += v[r]; }
        for (int off = 32; off; off >>= 1) sum += __shfl_down(sum, off, 64);
        if (lane == 0) red[wave] = sum;
        __syncthreads();
        sum = red[0] + red[1] + red[2] + red[3];
        float inv = 1.f / sum;
#pragma unroll
        for (int r = 0; r < 8; ++r)
            Acat[(size_t)n * 4096 + r * 256 + tid] = f2bf(v[r] * inv);
    } else if (bid < 6144) {
        size_t j = ((size_t)(bid - 2048) * 256 + tid) * 4;
        float4 v = *(const float4*)(adj + j);
        int n = (int)(j >> 11), c = (int)(j & 2047);
        ushort4 o = make_ushort4(f2bf(v.x), f2bf(v.y), f2bf(v.z), f2bf(v.w));
        *(ushort4*)(Acat + (size_t)n * 4096 + 2048 + c) = o;
    } else if (bid < 14336) {
        size_t j = ((size_t)(bid - 6144) * 256 + tid) * 4;
        float4 v = *(const float4*)(saw + j);
        ushort4 o = make_ushort4(f2bf(v.x), f2bf(v.y), f2bf(v.z), f2bf(v.w));
        *(ushort4*)(sawb + j) = o;
    } else if (bid < 15360) {
        int local = bid - 14336;
        int m0 = (local & 31) * 64, b = local >> 5;
        int c = tid & 63, g = tid >> 6;
#pragma unroll
        for (int r = 0; r < 16; ++r) {
            int mm = g * 16 + r;
            t[mm][c] = f2bf(x[((size_t)b * 2048 + m0 + mm) * 64 + c]);
        }
        __syncthreads();
#pragma unroll
        for (int r = 0; r < 16; ++r) {
            int cc = g * 16 + r;
            xtT[((size_t)b * 64 + cc) * 2048 + m0 + c] = t[c][cc];
        }
    } else {
        int local = bid - 15360;
        if (local < 16) {
            const int d = local;
            const float* base = Wp + (size_t)d * 12288;    // [k][i][o]
            for (int idx = tid; idx < 12288; idx += 256) {
                int o = idx / 192, ki = idx - o * 192;
                int k = ki >> 6, i = ki & 63;
                float v;
                if (k == 0)      v = base[i * 64 + o] - base[2 * 4096 + i * 64 + o];
                else if (k == 1) v = base[4096 + i * 64 + o];
                else             v = 2.f * base[2 * 4096 + i * 64 + o];
                Wpb[(size_t)(d * 64 + o) * 192 + ki] = f2bf(v);
            }
        } else {
            const int nb = local - 16;                     // 64 blocks x 32 n
#pragma unroll
            for (int it = 0; it < 8; ++it) {
                int idx = tid + it * 256;
                int n = nb * 32 + (idx >> 6), o = idx & 63;
                float s = 0.f;
#pragma unroll
                for (int d = 0; d < 16; ++d) s = fmaf(E[n * 16 + d], bp[d * 64 + o], s);
                bias[(size_t)n * 64 + o] = s;
            }
        }
    }
}

// ---------------------------------------------------------------- GEMM 128x128, BK=64, split-K
// C[m,n] = sum_k A[m,k]*Bt[n,k]; bf16 partial -> Cp + z*M*N.
__global__ __launch_bounds__(256, 3)
void gemm_bt(const u16* __restrict__ A, const u16* __restrict__ Bt,
             u16* __restrict__ Cp, int M, int N, int K, int Kh) {
    __shared__ alignas(16) u16 As[128 * 64];   // 16 KB
    __shared__ alignas(16) u16 Bs[128 * 64];   // 16 KB
    const int tid = threadIdx.x, lane = tid & 63, wave = tid >> 6;
    const int m0 = blockIdx.y * 128, n0 = blockIdx.x * 128;
    const int wm = (wave >> 1) * 64, wn = (wave & 1) * 64;
    const int kbeg = blockIdx.z * Kh, kend = kbeg + Kh;
    const int ml = lane & 15, c0l = lane >> 4;
    f32x4 acc[4][4] = {};

    int baseA[4], mskA[4], baseB[4], mskB[4];
#pragma unroll
    for (int i = 0; i < 4; ++i) { int m = wm + i * 16 + ml; baseA[i] = m * 8; mskA[i] = m & 7; }
#pragma unroll
    for (int j = 0; j < 4; ++j) { int nn = wn + j * 16 + ml; baseB[j] = nn * 8; mskB[j] = nn & 7; }

    for (int k0 = kbeg; k0 < kend; k0 += 64) {
#pragma unroll
        for (int r = 0; r < 4; ++r) {           // A: 1024 16B-chunks
            int s = wave * 64 + r * 256 + lane;
            int row = s >> 3, gc = (s & 7) ^ (row & 7);
            gl_lds16(A + (size_t)(m0 + row) * K + k0 + gc * 8, As + (size_t)s * 8);
        }
#pragma unroll
        for (int r = 0; r < 4; ++r) {           // B: 1024 16B-chunks
            int s = wave * 64 + r * 256 + lane;
            int row = s >> 3, gc = (s & 7) ^ (row & 7);
            gl_lds16(Bt + (size_t)(n0 + row) * K + k0 + gc * 8, Bs + (size_t)s * 8);
        }
        __syncthreads();
#pragma unroll
        for (int ks4 = 0; ks4 < 8; ks4 += 4) {
            bf16x8 af[4], bv[4];
#pragma unroll
            for (int i = 0; i < 4; ++i)
                af[i] = *(const bf16x8*)(As + (baseA[i] + ((c0l + ks4) ^ mskA[i])) * 8);
#pragma unroll
            for (int j = 0; j < 4; ++j)
                bv[j] = *(const bf16x8*)(Bs + (baseB[j] + ((c0l + ks4) ^ mskB[j])) * 8);
#pragma unroll
            for (int i = 0; i < 4; ++i)
#pragma unroll
                for (int j = 0; j < 4; ++j)
                    acc[i][j] = __builtin_amdgcn_mfma_f32_16x16x32_bf16(af[i], bv[j], acc[i][j], 0, 0, 0);
        }
        __syncthreads();
    }

    const int col_l = lane & 15, row_l = (lane >> 4) * 4;
    u16* Cz = Cp + (size_t)blockIdx.z * M * N;
#pragma unroll
    for (int i = 0; i < 4; ++i)
#pragma unroll
        for (int j = 0; j < 4; ++j)
#pragma unroll
            for (int r = 0; r < 4; ++r) {
                int row = m0 + wm + i * 16 + row_l + r;
                int col = n0 + wn + j * 16 + col_l;
                Cz[(size_t)row * N + col] = f2bf(acc[i][j][r]);
            }
}

// ---------------------------------------------------------------- split-K reduces
// S = sig(z)*adj + (1-sig(z))*sup;  sup + adj both from Acat (bf16)
__global__ __launch_bounds__(256)
void reduce_z(const u16* __restrict__ p, const u16* __restrict__ Acat,
              u16* __restrict__ S) {
    size_t j = ((size_t)blockIdx.x * 256 + threadIdx.x) * 4;
    ushort4 p0 = *(const ushort4*)(p + j);
    ushort4 p1 = *(const ushort4*)(p + PSTRIDE + j);
    ushort4 p2 = *(const ushort4*)(p + 2 * PSTRIDE + j);
    ushort4 p3 = *(const ushort4*)(p + 3 * PSTRIDE + j);
    int row = (int)(j >> 11), col = (int)(j & 2047);
    ushort4 sp = *(const ushort4*)(Acat + (size_t)row * 4096 + col);
    ushort4 ad = *(const ushort4*)(Acat + (size_t)row * 4096 + 2048 + col);
    float z0 = bf2f(p0.x) + bf2f(p1.x) + bf2f(p2.x) + bf2f(p3.x);
    float z1 = bf2f(p0.y) + bf2f(p1.y) + bf2f(p2.y) + bf2f(p3.y);
    float z2 = bf2f(p0.z) + bf2f(p1.z) + bf2f(p2.z) + bf2f(p3.z);
    float z3 = bf2f(p0.w) + bf2f(p1.w) + bf2f(p2.w) + bf2f(p3.w);
    float s0 = 1.f / (1.f + __expf(-z0)), s1 = 1.f / (1.f + __expf(-z1));
    float s2 = 1.f / (1.f + __expf(-z2)), s3 = 1.f / (1.f + __expf(-z3));
    ushort4 o = make_ushort4(
        f2bf(s0 * bf2f(ad.x) + (1.f - s0) * bf2f(sp.x)),
        f2bf(s1 * bf2f(ad.y) + (1.f - s1) * bf2f(sp.y)),
        f2bf(s2 * bf2f(ad.z) + (1.f - s2) * bf2f(sp.z)),
        f2bf(s3 * bf2f(ad.w) + (1.f - s3) * bf2f(sp.w)));
    *(ushort4*)(S + j) = o;
}

// G1 reduce: xg1b[b,n,c] (gconv A layout) + xg1T[(b,c)][n] (G2 Bt operand)
__global__ __launch_bounds__(256)
void reduceT(const u16* __restrict__ p, u16* __restrict__ xg1b,
             u16* __restrict__ xg1T) {
    __shared__ u16 t[64][68];
    int bx = blockIdx.x * 64, by = blockIdx.y * 64;   // bx: (b,c) cols, by: n rows
    int cg = threadIdx.x & 15, rg = threadIdx.x >> 4;
    int b = bx >> 6;
#pragma unroll
    for (int rr = 0; rr < 4; ++rr) {
        int row = rg * 4 + rr;
        size_t idx = (size_t)(by + row) * 2048 + bx + cg * 4;
        ushort4 q0 = *(const ushort4*)(p + idx);
        ushort4 q1 = *(const ushort4*)(p + PSTRIDE + idx);
        ushort4 q2 = *(const ushort4*)(p + 2 * PSTRIDE + idx);
        ushort4 q3 = *(const ushort4*)(p + 3 * PSTRIDE + idx);
        ushort4 v = make_ushort4(
            f2bf(bf2f(q0.x) + bf2f(q1.x) + bf2f(q2.x) + bf2f(q3.x)),
            f2bf(bf2f(q0.y) + bf2f(q1.y) + bf2f(q2.y) + bf2f(q3.y)),
            f2bf(bf2f(q0.z) + bf2f(q1.z) + bf2f(q2.z) + bf2f(q3.z)),
            f2bf(bf2f(q0.w) + bf2f(q1.w) + bf2f(q2.w) + bf2f(q3.w)));
        *(ushort4*)(xg1b + ((size_t)b * 2048 + by + row) * 64 + cg * 4) = v;
        *(ushort4*)(&t[row][cg * 4]) = v;
    }
    __syncthreads();
    int c = threadIdx.x & 63, g = threadIdx.x >> 6;
#pragma unroll
    for (int r = 0; r < 16; ++r) {
        int row = g * 16 + r;
        xg1T[(size_t)(bx + row) * 2048 + by + c] = t[c][row];
    }
}

// ---------------------------------------------------------------- gconv MFMA (fused G2 reduce)
// out[row=(b,n), o] = bias[n,o] + sum_d E[n,d] * (XG[row,:] @ Wp'_d)   K=192
// XG cols: [x (fp32, cast here) | xg1b | sum of 4 G2 partials].
// A-staging via plain loads + ds_write (gl_lds16 under divergence is UNDEFINED — R6 bug).
__global__ __launch_bounds__(256, 2)
void gconv_mfma(const float* __restrict__ x, const u16* __restrict__ xg1,
                const u16* __restrict__ p, const u16* __restrict__ Wpb,
                const float* __restrict__ bias, const float* __restrict__ E,
                float* __restrict__ out) {
    __shared__ alignas(16) u16 As[128 * 192];   // 48 KB, XOR-swizzled chunks
    __shared__ alignas(16) u16 Bs[64 * 192];    // 24 KB
    __shared__ float El[16 * 128];              //  8 KB, [d][row]
    const int tid = threadIdx.x, lane = tid & 63, wave = tid >> 6;
    const int m0 = blockIdx.x * 128, nb = m0 & 2047, bB = m0 >> 11;
    const int wm = (wave >> 1) * 64, wn = (wave & 1) * 32;
    const int ml = lane & 15, c0l = lane >> 4;
    const int col_l = lane & 15, rl = (lane >> 4) * 4;

    // stage A: 128 rows x 24 chunks; slot sc holds global chunk (sc&24)|((sc^row)&7)
#pragma unroll
    for (int it = 0; it < 12; ++it) {
        int s = tid + it * 256;
        int row = s / 24, sc = s - row * 24;
        int gc = (sc & 24) | ((sc ^ row) & 7);
        int grow = m0 + row;
        u16x8 v;
        if (gc < 8) {
            const float* xp = x + (size_t)grow * 64 + gc * 8;
            float4 a = *(const float4*)xp, b4 = *(const float4*)(xp + 4);
            v[0] = f2bf(a.x);  v[1] = f2bf(a.y);  v[2] = f2bf(a.z);  v[3] = f2bf(a.w);
            v[4] = f2bf(b4.x); v[5] = f2bf(b4.y); v[6] = f2bf(b4.z); v[7] = f2bf(b4.w);
        } else if (gc < 16) {
            v = *(const u16x8*)(xg1 + (size_t)grow * 64 + (gc & 7) * 8);
        } else {
            int n = grow & 2047, c8 = (gc & 7) * 8;
            const u16* pp = p + (size_t)n * 2048 + bB * 64 + c8;
            u16x8 q0 = *(const u16x8*)pp;
            u16x8 q1 = *(const u16x8*)(pp + PSTRIDE);
            u16x8 q2 = *(const u16x8*)(pp + 2 * PSTRIDE);
            u16x8 q3 = *(const u16x8*)(pp + 3 * PSTRIDE);
#pragma unroll
            for (int tt = 0; tt < 8; ++tt)
                v[tt] = f2bf(bf2f(q0[tt]) + bf2f(q1[tt]) + bf2f(q2[tt]) + bf2f(q3[tt]));
        }
        *(u16x8*)(As + (size_t)s * 8) = v;
    }
    // stage El transposed [d][128]
#pragma unroll
    for (int it = 0; it < 8; ++it) {
        int idx = tid + it * 256;
        El[idx] = E[(size_t)(nb + (idx & 127)) * 16 + (idx >> 7)];
    }
    // init out-acc from bias
    f32x4 oacc[4][2];
#pragma unroll
    for (int i = 0; i < 4; ++i)
#pragma unroll
        for (int j = 0; j < 2; ++j)
#pragma unroll
            for (int r = 0; r < 4; ++r)
                oacc[i][j][r] = bias[(size_t)(nb + wm + i * 16 + rl + r) * 64 + wn + j * 16 + col_l];
    __syncthreads();

    // preload A fragments (d-invariant): af[i][ks]
    bf16x8 af[4][6];
#pragma unroll
    for (int i = 0; i < 4; ++i) {
        int m = wm + i * 16 + ml, base = m * 24, msk = m & 7;
#pragma unroll
        for (int ks = 0; ks < 6; ++ks) {
            int c = c0l + ks * 4;
            af[i][ks] = *(const bf16x8*)(As + (base + ((c & 24) | ((c ^ msk) & 7))) * 8);
        }
    }

    for (int d = 0; d < 16; ++d) {
        if (d) __syncthreads();                 // protect Bs from overwrite
#pragma unroll
        for (int it = 0; it < 6; ++it) {        // stage Wp'_d: 64 rows x 24 chunks
            int s = tid + it * 256;             // full-wave, lane-linear -> gl_lds16 OK
            int row = s / 24, sc = s - row * 24;
            int gc = (sc & 24) | ((sc ^ row) & 7);
            gl_lds16(Wpb + (size_t)(d * 64 + row) * 192 + gc * 8, Bs + (size_t)s * 8);
        }
        __syncthreads();
        f32x4 tmp[4][2] = {};
#pragma unroll
        for (int ks = 0; ks < 6; ++ks) {
            bf16x8 bv[2];
#pragma unroll
            for (int j = 0; j < 2; ++j) {
                int o = wn + j * 16 + ml, msk = o & 7, c = c0l + ks * 4;
                bv[j] = *(const bf16x8*)(Bs + (o * 24 + ((c & 24) | ((c ^ msk) & 7))) * 8);
            }
#pragma unroll
            for (int i = 0; i < 4; ++i)
#pragma unroll
                for (int j = 0; j < 2; ++j)
                    tmp[i][j] = __builtin_amdgcn_mfma_f32_16x16x32_bf16(af[i][ks], bv[j], tmp[i][j], 0, 0, 0);
        }
        // scale-add: oacc += E[row,d] * tmp
#pragma unroll
        for (int i = 0; i < 4; ++i)
#pragma unroll
            for (int r = 0; r < 4; ++r) {
                float ev = El[d * 128 + wm + i * 16 + rl + r];
#pragma unroll
                for (int j = 0; j < 2; ++j)
                    oacc[i][j][r] = fmaf(ev, tmp[i][j][r], oacc[i][j][r]);
            }
    }
#pragma unroll
    for (int i = 0; i < 4; ++i)
#pragma unroll
        for (int j = 0; j < 2; ++j)
#pragma unroll
            for (int r = 0; r < 4; ++r)
                out[(size_t)(m0 + wm + i * 16 + rl + r) * 64 + wn + j * 16 + col_l] = oacc[i][j][r];
}

// ---------------------------------------------------------------- launch
extern "C" void kernel_launch(void* const* d_in, const int* in_sizes, int n_in,
                              void* d_out, int out_size, void* d_ws, size_t ws_size,
                              hipStream_t stream) {
    const float* x   = (const float*)d_in[0];   // [32,2048,64]
    const float* E   = (const float*)d_in[1];   // [2048,16]
    const float* adj = (const float*)d_in[2];   // [2048,2048]
    const float* Wp  = (const float*)d_in[3];   // [16,3,64,64]
    const float* bp  = (const float*)d_in[4];   // [16,64]
    const float* saw = (const float*)d_in[5];   // [2048,4096]
    float* out = (float*)d_out;

    char* ws = (char*)d_ws;
    const size_t MB = 1u << 20;
    u16*   Acat  = (u16*)(ws);                  // [0,16M)
    u16*   sawb  = (u16*)(ws + 16 * MB);        // [16,32M)
    u16*   XtT   = (u16*)(ws + 32 * MB);        // [32,40M)
    u16*   Wpb   = (u16*)(ws + 40 * MB);        // [40,40.4M)
    float* bias  = (float*)(ws + 41 * MB);      // [41,41.5M)
    u16*   part  = (u16*)(ws + 48 * MB);        // [48,80M) 4 x 8MB bf16 partials
    u16*   S_bf  = (u16*)(ws + 16 * MB);        // [16,24M) after sawb dead
    u16*   xg1T  = (u16*)(ws + 24 * MB);        // [24,32M) after sawb dead
    u16*   xg1b  = (u16*)(ws);                  // [0,8M)   after Acat dead (post reduce_z)

    preamble<<<15440, 256, 0, stream>>>(E, adj, saw, x, Wp, bp, Acat, sawb, XtT, Wpb, bias);

    // z = Acat @ sawb^T, split-K=4
    gemm_bt<<<dim3(16, 16, 4), 256, 0, stream>>>(Acat, sawb, part, 2048, 2048, 4096, 1024);
    reduce_z<<<4096, 256, 0, stream>>>(part, Acat, S_bf);
    // G1: xg1 = S @ X, split-K=4
    gemm_bt<<<dim3(16, 16, 4), 256, 0, stream>>>(S_bf, XtT, part, 2048, 2048, 2048, 512);
    reduceT<<<dim3(32, 32), 256, 0, stream>>>(part, xg1b, xg1T);
    // G2: xg2raw = S @ xg1, split-K=4 (partials consumed directly by gconv)
    gemm_bt<<<dim3(16, 16, 4), 256, 0, stream>>>(S_bf, xg1T, part, 2048, 2048, 2048, 512);

    gconv_mfma<<<512, 256, 0, stream>>>(x, xg1b, part, Wpb, bias, E, out);
}